// Round 5
// baseline (630.845 us; speedup 1.0000x reference)
//
#include <hip/hip_runtime.h>
#include <stdint.h>

typedef unsigned long long u64;
typedef unsigned short ushort_t;
typedef __attribute__((ext_vector_type(8))) short short8;
typedef __attribute__((ext_vector_type(8))) _Float16 half8;
typedef __attribute__((ext_vector_type(16))) float f32x16;

// Dims: B=512,N=100 -> M=51200; T=100, L=50 conv pos, HE=64, E=128, NE=512, HD=256.

// ---------------- workspace layout (float offsets) ----------------
#define WS_RNP0     0ll          // 51200 f32 (rownorm; full sum here)  -> end    51,200
#define WS_RNP1     51200ll      // 51200 f32 (zeroed by encoder)       -> end   102,400
#define WS_ZHI      102400ll     // 51200*128 ushort = 3,276,800 f     -> end 3,379,200
#define WS_ZLO      3379200ll    // 3,276,800 f                        -> end 6,656,000
#define WS_ENCBHI   6656000ll    // 12288 ushort = 6144 f              -> end 6,662,144
#define WS_ENCBLO   6662144ll    // 6144 f                             -> end 6,668,288
#define WS_CBHI     6668288ll    // 65536 ushort = 32768 f             -> end 6,701,056
#define WS_CBLO     6701056ll    // 32768 f                            -> end 6,733,824
#define WS_CBNORM   6733824ll    // 512 f                              -> end 6,734,336
#define WS_D1F      6734336ll    // 32768 ushort = 16384 f             -> end 6,750,720
#define WS_D2F      6750720ll    // 65536 ushort = 32768 f             -> end 6,783,488
#define WS_D3F      6783488ll    // 32768 ushort = 16384 f             -> end 6,799,872
#define WS_ACCUMS   6799872ll    // 8 f32                              -> end 6,799,880
#define WS_GBEST    6799880ll    // 51200 u64 = 102,400 f (byte%8==0)  -> end 6,902,280
#define WS_H1       6902280ll    // 51200*256 ushort = 6,553,600 f     -> end 13,455,880
#define WS_H2       13455880ll   // 6,553,600 f                        -> end 20,009,480 (~80 MB)

__device__ __host__ inline ushort_t bf16_rn(float v) {
  unsigned u = __float_as_uint(v);
  unsigned r = (u + 0x7fffu + ((u >> 16) & 1u)) >> 16;
  return (ushort_t)r;
}
union h2u { _Float16 h; unsigned short u; };
union s2h { short8 s; half8 h; };

// packed RNE f32x2 -> bf16x2 (v_cvt_pk_bf16_f32); low 16 bits = a, high = b.
// No builtin on gfx950 (guide T12) -> inline asm. RNE matches bf16_rn for finite vals.
__device__ inline unsigned pk2_bf16(float a, float b) {
  unsigned r;
  asm("v_cvt_pk_bf16_f32 %0, %1, %2" : "=v"(r) : "v"(a), "v"(b));
  return r;
}

__device__ inline int rowfn(int r, int half) { return (r & 3) + 8*(r >> 2) + 4*half; }

#define MFMA_BF16 __builtin_amdgcn_mfma_f32_32x32x16_bf16

// ---------------- prep: frag-pack all weights + codebook norms ----------------
__global__ __launch_bounds__(256) void prep_kernel(
    const float* __restrict__ w2, const float* __restrict__ cb,
    const float* __restrict__ d1w, const float* __restrict__ d2w,
    const float* __restrict__ d3w,
    ushort_t* __restrict__ ebhi, ushort_t* __restrict__ eblo,
    ushort_t* __restrict__ cbhi, ushort_t* __restrict__ cblo,
    ushort_t* __restrict__ d1f, ushort_t* __restrict__ d2f,
    ushort_t* __restrict__ d3f, float* __restrict__ cbnorm)
{
  const int total = 12288 + 65536 + 32768 + 65536 + 32768 + 512;
  for (int i = blockIdx.x*256 + threadIdx.x; i < total; i += gridDim.x*256) {
    int idx = i;
    if (idx < 12288) {
      // encoder conv2 B-frags (bf16 hi/lo), 32x32x16: f=((t*2+nt)*4+kt)
      int j = idx & 7, l6 = (idx >> 3) & 63, f = idx >> 9;
      int kt = f & 3, ntt = (f >> 2) & 1, t = f >> 3;
      int oc = ntt*32 + (l6 & 31);
      int ic = kt*16 + (l6 >> 5)*8 + j;
      float v = w2[(oc*64 + ic)*3 + t];
      ushort_t hi = bf16_rn(v);
      float hf = __uint_as_float(((unsigned)hi) << 16);
      ebhi[idx] = hi; eblo[idx] = bf16_rn(v - hf); continue;
    }
    idx -= 12288;
    if (idx < 65536) {
      // codebook f16 hi/lo frags, scaled x512: ntg16 x kt8
      int j = idx & 7, l6 = (idx >> 3) & 63, f = idx >> 9;
      int kt = f & 7, ntg = f >> 3;
      int k = kt*16 + (l6 >> 5)*8 + j;
      int n = ntg*32 + (l6 & 31);
      float v = cb[n*128 + k] * 512.0f;
      h2u a, b; a.h = (_Float16)v;
      b.h = (_Float16)(v - (float)a.h);
      cbhi[idx] = a.u; cblo[idx] = b.u; continue;
    }
    idx -= 65536;
    if (idx < 32768) {
      int j = idx & 7, l6 = (idx >> 3) & 63, f = idx >> 9;
      int kt = f & 7, ntg = f >> 3;
      int k = kt*16 + (l6 >> 5)*8 + j;
      int n = ntg*32 + (l6 & 31);
      d1f[idx] = bf16_rn(d1w[n*128 + k]); continue;
    }
    idx -= 32768;
    if (idx < 65536) {
      int j = idx & 7, l6 = (idx >> 3) & 63, f = idx >> 9;
      int kt = f & 15, ntg = f >> 4;
      int k = kt*16 + (l6 >> 5)*8 + j;
      int n = ntg*32 + (l6 & 31);
      d2f[idx] = bf16_rn(d2w[n*256 + k]); continue;
    }
    idx -= 65536;
    if (idx < 32768) {
      int j = idx & 7, l6 = (idx >> 3) & 63, f = idx >> 9;
      int kt = f & 15, ntg = f >> 4;
      int k = kt*16 + (l6 >> 5)*8 + j;
      int n = ntg*32 + (l6 & 31);
      d3f[idx] = (n < 100) ? bf16_rn(d3w[n*256 + k]) : (ushort_t)0; continue;
    }
    idx -= 32768;
    { double s = 0.0; const float* c = cb + idx*128;
      for (int e = 0; e < 128; ++e) { double v = (double)c[e]; s += v*v; }
      cbnorm[idx] = (float)s; }
  }
}

// ---------------- encoder v4: ONE WAVE PER m, ZERO barriers ----------------
// 4 independent m per 256-thread block; each wave owns a private 14.1KB LDS slice.
// H layout per m: 52 rows x 272B (hi bf16 oc0..63 | lo bf16 oc0..63 | 16B pad).
// Intra-wave producer->consumer ordering via inline lgkmcnt(0) + sched_barrier
// (rule #18). No __syncthreads anywhere -> no barrier-drain stalls.
// w1,b1,b2,latw,latb NOT __restrict (wave-uniform s_loads / L1).
__global__ __launch_bounds__(256, 2) void encoder_kernel(
    const float* __restrict__ x, const float* __restrict__ tm,
    const float* __restrict__ imask,
    const float* w1, const float* b1,
    const ushort_t* __restrict__ ebhi, const ushort_t* __restrict__ eblo,
    const float* b2, const float* latw, const float* latb,
    ushort_t* zhi, ushort_t* zlo, float* rnp0, float* rnp1)
{
  __shared__ ushort_t s_H[4][52*136];   // 56,576 B
  __shared__ float s_red[4][64];        //  1,024 B  (total 57.6KB -> 2 blocks/CU)
  const int tid  = threadIdx.x;
  const int wv   = __builtin_amdgcn_readfirstlane((int)(tid >> 6));
  const int lane = tid & 63;
  const int ln31 = lane & 31, half = lane >> 5;
  const long m   = (long)blockIdx.x*4 + wv;     // wave-uniform
  const float imv = imask[m];                   // scalar load
  ushort_t* Hw  = s_H[wv];
  float* redw   = s_red[wv];

  // ---- conv1: inputs straight from global (x[t]=x[pos*2+c] -> 3 float2 per lane) ----
  {
    const int p = (lane < 50) ? lane : 0;
    const long xb = m*100 + 2*p;
    const float2 x0v = *(const float2*)(x + xb);
    const float2 t0v = *(const float2*)(tm + xb);
    float2 xmv = {0.f, 0.f}, tmv = {0.f, 0.f};
    float2 xpv = {0.f, 0.f}, tpv = {0.f, 0.f};
    if (p > 0)  { xmv = *(const float2*)(x + xb - 2); tmv = *(const float2*)(tm + xb - 2); }
    if (p < 49) { xpv = *(const float2*)(x + xb + 2); tpv = *(const float2*)(tm + xb + 2); }
    const float a0 = xmv.x*tmv.x, c0 = xmv.y*tmv.y;
    const float a1 = x0v.x*t0v.x, c1 = x0v.y*t0v.y;
    const float a2 = xpv.x*tpv.x, c2 = xpv.y*tpv.y;
    const int row = lane + 1;
    #pragma unroll
    for (int g = 0; g < 4; ++g) {
      unsigned hi8[8], lo8[8];
      #pragma unroll
      for (int pr = 0; pr < 8; ++pr) {
        const int o = g*16 + pr*2;
        const float* wA = w1 + (long)o*6;       // wave-uniform -> s_load
        const float* wB = wA + 6;
        float sA = 0.f, sB = 0.f;
        sA = fmaf(wA[0], a0, sA); sA = fmaf(wA[1], a1, sA); sA = fmaf(wA[2], a2, sA);
        sA = fmaf(wA[3], c0, sA); sA = fmaf(wA[4], c1, sA); sA = fmaf(wA[5], c2, sA);
        sB = fmaf(wB[0], a0, sB); sB = fmaf(wB[1], a1, sB); sB = fmaf(wB[2], a2, sB);
        sB = fmaf(wB[3], c0, sB); sB = fmaf(wB[4], c1, sB); sB = fmaf(wB[5], c2, sB);
        const float hA = fmaxf(fmaf(imv, sA, b1[o]),     0.f);
        const float hB = fmaxf(fmaf(imv, sB, b1[o + 1]), 0.f);
        const unsigned h = pk2_bf16(hA, hB);
        const float ha = __uint_as_float(h << 16);
        const float hb = __uint_as_float(h & 0xffff0000u);
        lo8[pr] = pk2_bf16(hA - ha, hB - hb);
        hi8[pr] = h;
      }
      if (lane < 50) {
        short8* dh = (short8*)(Hw + row*136 + g*16);
        dh[0] = *(short8*)&hi8[0]; dh[1] = *(short8*)&hi8[4];
        short8* dl = (short8*)(Hw + row*136 + 64 + g*16);
        dl[0] = *(short8*)&lo8[0]; dl[1] = *(short8*)&lo8[4];
      }
    }
    if (lane == 50 || lane == 51) {          // zero halo rows 0 and 51
      const int zr = (lane == 50) ? 0 : 51;
      short8 z8 = {};
      short8* d = (short8*)(Hw + zr*136);
      #pragma unroll
      for (int i = 0; i < 16; ++i) d[i] = z8;
    }
  }
  // intra-wave LDS write->read fence (no barrier needed: wave-private slice)
  asm volatile("s_waitcnt lgkmcnt(0)" ::: "memory");
  __builtin_amdgcn_sched_barrier(0);

  // ---- conv2 MFMA: this wave does all 4 (mt,nt) tiles of its own m ----
  f32x16 acc00, acc01, acc10, acc11;
  #pragma unroll
  for (int q = 0; q < 16; ++q) { acc00[q] = 0.f; acc01[q] = 0.f; acc10[q] = 0.f; acc11[q] = 0.f; }
  {
    const short8* bh8 = (const short8*)ebhi;
    const short8* bl8 = (const short8*)eblo;
    const short8* H8  = (const short8*)Hw;    // short8 stride 17 per row
    for (int t = 0; t < 3; ++t) {
      const int r0 = ln31 + t;                // 0..33 (valid)
      int r1 = 32 + ln31 + t;                 // 32..65 -> clamp to zero halo row 51
      if (r1 > 51) r1 = 51;
      const int a0b = r0*17 + half;
      const int a1b = r1*17 + half;
      #pragma unroll
      for (int kt = 0; kt < 4; ++kt) {
        const int f0 = (t*2 + 0)*4 + kt;
        const int f1 = (t*2 + 1)*4 + kt;
        const short8 Bh0 = bh8[f0*64 + lane], Bl0 = bl8[f0*64 + lane];
        const short8 Bh1 = bh8[f1*64 + lane], Bl1 = bl8[f1*64 + lane];
        const short8 ah0 = H8[a0b + kt*2], al0 = H8[a0b + kt*2 + 8];
        const short8 ah1 = H8[a1b + kt*2], al1 = H8[a1b + kt*2 + 8];
        acc00 = MFMA_BF16(ah0, Bh0, acc00, 0, 0, 0);
        acc00 = MFMA_BF16(ah0, Bl0, acc00, 0, 0, 0);
        acc00 = MFMA_BF16(al0, Bh0, acc00, 0, 0, 0);
        acc01 = MFMA_BF16(ah0, Bh1, acc01, 0, 0, 0);
        acc01 = MFMA_BF16(ah0, Bl1, acc01, 0, 0, 0);
        acc01 = MFMA_BF16(al0, Bh1, acc01, 0, 0, 0);
        acc10 = MFMA_BF16(ah1, Bh0, acc10, 0, 0, 0);
        acc10 = MFMA_BF16(ah1, Bl0, acc10, 0, 0, 0);
        acc10 = MFMA_BF16(al1, Bh0, acc10, 0, 0, 0);
        acc11 = MFMA_BF16(ah1, Bh1, acc11, 0, 0, 0);
        acc11 = MFMA_BF16(ah1, Bl1, acc11, 0, 0, 0);
        acc11 = MFMA_BF16(al1, Bh1, acc11, 0, 0, 0);
      }
    }
  }

  // ---- relu + bias + masked position-sum (all in-wave) ----
  {
    const float bv0 = b2[ln31];
    const float bv1 = b2[32 + ln31];
    float s0 = 0.f, s1 = 0.f;
    #pragma unroll
    for (int r = 0; r < 16; ++r) {
      s0 += fmaxf(acc00[r] + bv0, 0.f);              // mt=0: pos 0..31 all valid
      s1 += fmaxf(acc01[r] + bv1, 0.f);
      const int mpos = 32 + rowfn(r, half);          // mt=1: keep pos<50
      const float v10 = fmaxf(acc10[r] + bv0, 0.f);
      const float v11 = fmaxf(acc11[r] + bv1, 0.f);
      if (mpos < 50) { s0 += v10; s1 += v11; }
    }
    s0 += __shfl_xor(s0, 32);
    s1 += __shfl_xor(s1, 32);
    if (half == 0) { redw[ln31] = s0; redw[32 + ln31] = s1; }
  }
  asm volatile("s_waitcnt lgkmcnt(0)" ::: "memory");
  __builtin_amdgcn_sched_barrier(0);

  // ---- latent: each lane computes e=lane and e=lane+64 ----
  {
    const int e0 = lane, e1 = lane + 64;
    const float4* lw0 = (const float4*)(latw + (long)e0*64);
    const float4* lw1 = (const float4*)(latw + (long)e1*64);
    const float4* rp  = (const float4*)redw;         // wave-uniform -> LDS broadcast
    float A0 = 0.f, B0 = 0.f, A1 = 0.f, B1 = 0.f;
    #pragma unroll
    for (int q = 0; q < 16; q += 2) {
      const float4 ra = rp[q], rb = rp[q + 1];
      const float4 wa0 = lw0[q], wb0 = lw0[q + 1];
      const float4 wa1 = lw1[q], wb1 = lw1[q + 1];
      A0 = fmaf(wa0.x, ra.x, A0); A0 = fmaf(wa0.y, ra.y, A0);
      A0 = fmaf(wa0.z, ra.z, A0); A0 = fmaf(wa0.w, ra.w, A0);
      B0 = fmaf(wb0.x, rb.x, B0); B0 = fmaf(wb0.y, rb.y, B0);
      B0 = fmaf(wb0.z, rb.z, B0); B0 = fmaf(wb0.w, rb.w, B0);
      A1 = fmaf(wa1.x, ra.x, A1); A1 = fmaf(wa1.y, ra.y, A1);
      A1 = fmaf(wa1.z, ra.z, A1); A1 = fmaf(wa1.w, ra.w, A1);
      B1 = fmaf(wb1.x, rb.x, B1); B1 = fmaf(wb1.y, rb.y, B1);
      B1 = fmaf(wb1.w, rb.w, B1); B1 = fmaf(wb1.z, rb.z, B1);
    }
    const float z0 = fmaf(0.02f, A0 + B0, latb[e0]) * imv;
    const float z1 = fmaf(0.02f, A1 + B1, latb[e1]) * imv;
    h2u zh0, zl0, zh1, zl1;
    zh0.h = (_Float16)z0; zl0.h = (_Float16)(z0 - (float)zh0.h);
    zh1.h = (_Float16)z1; zl1.h = (_Float16)(z1 - (float)zh1.h);
    zhi[m*128 + e0] = zh0.u; zhi[m*128 + e1] = zh1.u;
    zlo[m*128 + e0] = zl0.u; zlo[m*128 + e1] = zl1.u;
    float v = z0*z0 + z1*z1;
    #pragma unroll
    for (int off = 32; off > 0; off >>= 1) v += __shfl_down(v, off);
    if (lane == 0) { rnp0[m] = v; rnp1[m] = 0.f; }
  }
}

// ---------------- VQ: f16 3-pass MFMA, 32 rows x all 512 codes per block ----------------
__global__ __launch_bounds__(256) void vq_kernel(
    const ushort_t* __restrict__ zhi, const ushort_t* __restrict__ zlo,
    const ushort_t* __restrict__ cbhi, const ushort_t* __restrict__ cblo,
    const float* __restrict__ rnp0, const float* __restrict__ rnp1,
    const float* __restrict__ cbnorm, u64* __restrict__ gbest)
{
  __shared__ ushort_t s_ah[32*136];
  __shared__ ushort_t s_al[32*136];
  __shared__ float s_rn[32];
  __shared__ u64 s_best[32];
  const int tid = threadIdx.x;
  const int m0 = blockIdx.x * 32;
  {
    const short8* gh = (const short8*)(zhi + (long)m0*128);
    const short8* gl = (const short8*)(zlo + (long)m0*128);
    const int row = tid >> 3, c8 = (tid & 7)*2;
    ((short8*)s_ah)[row*17 + c8]     = gh[tid*2];
    ((short8*)s_ah)[row*17 + c8 + 1] = gh[tid*2 + 1];
    ((short8*)s_al)[row*17 + c8]     = gl[tid*2];
    ((short8*)s_al)[row*17 + c8 + 1] = gl[tid*2 + 1];
  }
  if (tid < 32) { s_rn[tid] = rnp0[m0 + tid] + rnp1[m0 + tid]; s_best[tid] = ~0ULL; }
  __syncthreads();

  const int wv = tid >> 6, lane = tid & 63;
  const int ln31 = lane & 31, half = lane >> 5;
  float rnv[16];
  #pragma unroll
  for (int r = 0; r < 16; ++r) rnv[r] = s_rn[rowfn(r, half)];

  u64 best[16];
  #pragma unroll
  for (int r = 0; r < 16; ++r) best[r] = ~0ULL;

  const short8* ch8 = (const short8*)cbhi;
  const short8* cl8 = (const short8*)cblo;
  for (int ct = 0; ct < 4; ++ct) {
    const int ntg = wv*4 + ct;
    half8 Bh[8], Bl[8];
    #pragma unroll
    for (int kt = 0; kt < 8; ++kt) {
      s2h a, b;
      a.s = ch8[(ntg*8 + kt)*64 + lane];
      b.s = cl8[(ntg*8 + kt)*64 + lane];
      Bh[kt] = a.h; Bl[kt] = b.h;
    }
    f32x16 acc;
    #pragma unroll
    for (int q = 0; q < 16; ++q) acc[q] = 0.f;
    const int base8 = ln31*17 + half;
    #pragma unroll
    for (int kt = 0; kt < 8; ++kt) {
      s2h ah, al;
      ah.s = ((const short8*)s_ah)[base8 + kt*2];
      al.s = ((const short8*)s_al)[base8 + kt*2];
      acc = __builtin_amdgcn_mfma_f32_32x32x16_f16(ah.h, Bh[kt], acc, 0, 0, 0);
      acc = __builtin_amdgcn_mfma_f32_32x32x16_f16(ah.h, Bl[kt], acc, 0, 0, 0);
      acc = __builtin_amdgcn_mfma_f32_32x32x16_f16(al.h, Bh[kt], acc, 0, 0, 0);
    }
    const int code = ntg*32 + ln31;
    const float nrm = cbnorm[code];
    #pragma unroll
    for (int r = 0; r < 16; ++r) {
      const float t = fmaf(-0.00390625f, acc[r], rnv[r]);  // A - p/256 (cb scaled x512)
      const float d = t + nrm;
      const u64 pk = ((u64)__float_as_uint(d) << 32) | (u64)(unsigned)code;
      if (pk < best[r]) best[r] = pk;
    }
  }
  #pragma unroll
  for (int r = 0; r < 16; ++r) atomicMin(&s_best[rowfn(r, half)], best[r]);
  __syncthreads();
  if (tid < 32) gbest[m0 + tid] = s_best[tid];
}

// ---------------- decoder GEMM 1 + fused indices/vq-loss/S_im ----------------
__global__ __launch_bounds__(256) void dec1_kernel(
    const float* __restrict__ cb, const u64* __restrict__ gbest,
    const float* __restrict__ imask, const ushort_t* __restrict__ bfrag,
    const float* __restrict__ bias, ushort_t* __restrict__ h1out,
    float* __restrict__ out_idx, float* __restrict__ accums)
{
  __shared__ ushort_t s_a[64*136];
  __shared__ int s_idx[64];
  __shared__ float s_act[64];
  const int tid = threadIdx.x;
  const long m0 = (long)blockIdx.x * 64;
  if (tid < 64) {
    const u64 pk = gbest[m0 + tid];
    const int ii = (int)(unsigned)(pk & 0xffffffffULL);
    const float dd = __uint_as_float((unsigned)(pk >> 32));
    const float imv = imask[m0 + tid];
    s_idx[tid] = ii; s_act[tid] = imv;
    out_idx[m0 + tid] = (imv > 0.f) ? (float)ii : -1.0f;
    float vqp = 1.25f * dd * (1.0f/128.0f) * imv;
    float sim = imv;
    #pragma unroll
    for (int off = 32; off > 0; off >>= 1) {
      vqp += __shfl_down(vqp, off); sim += __shfl_down(sim, off);
    }
    if (tid == 0) { atomicAdd(&accums[1], vqp); atomicAdd(&accums[3], sim); }
  }
  __syncthreads();
  {
    const int row = tid >> 2, seg = tid & 3;
    const float4* src = (const float4*)(cb + (long)s_idx[row]*128 + seg*32);
    const float im = s_act[row];
    ushort_t tmp[32];
    #pragma unroll
    for (int q = 0; q < 8; ++q) {
      const float4 v = src[q];
      tmp[q*4+0] = bf16_rn(v.x*im); tmp[q*4+1] = bf16_rn(v.y*im);
      tmp[q*4+2] = bf16_rn(v.z*im); tmp[q*4+3] = bf16_rn(v.w*im);
    }
    short8* dst = (short8*)(s_a + row*136 + seg*32);
    #pragma unroll
    for (int q = 0; q < 4; ++q) dst[q] = *(short8*)&tmp[q*8];
  }
  __syncthreads();
  const int wv = tid >> 6, lane = tid & 63;
  const int ln31 = lane & 31, half = lane >> 5;
  const short8* bf = (const short8*)bfrag;
  #pragma unroll
  for (int nti = 0; nti < 2; ++nti) {
    const int ntg = wv + nti*4;
    short8 B[8];
    #pragma unroll
    for (int kt = 0; kt < 8; ++kt) B[kt] = bf[(ntg*8 + kt)*64 + lane];
    const float bv = bias[ntg*32 + ln31];
    #pragma unroll
    for (int mtl = 0; mtl < 2; ++mtl) {
      f32x16 acc;
      #pragma unroll
      for (int q = 0; q < 16; ++q) acc[q] = 0.f;
      const int base8 = (mtl*32 + ln31)*17 + half;
      #pragma unroll
      for (int kt = 0; kt < 8; ++kt) {
        const short8 a = ((const short8*)s_a)[base8 + kt*2];
        acc = MFMA_BF16(a, B[kt], acc, 0, 0, 0);
      }
      const int col = ntg*32 + ln31;
      #pragma unroll
      for (int r = 0; r < 16; ++r) {
        const long row = m0 + mtl*32 + rowfn(r, half);
        h1out[row*256 + col] = bf16_rn(fmaxf(acc[r] + bv, 0.f));
      }
    }
  }
}

// ---------------- decoder GEMM 2: h2 = relu(h1 @ d2^T + b), K=256 ----------------
__global__ __launch_bounds__(256) void dec2_kernel(
    const ushort_t* __restrict__ ain, const ushort_t* __restrict__ bfrag,
    const float* __restrict__ bias, ushort_t* __restrict__ outbuf)
{
  __shared__ ushort_t s_a[64*264];
  const int tid = threadIdx.x;
  const long m0 = (long)blockIdx.x * 64;
  {
    const int row = tid >> 2, seg = tid & 3;
    const short8* src = (const short8*)(ain + (m0 + row)*256 + seg*64);
    short8* dst = (short8*)(s_a + row*264 + seg*64);
    #pragma unroll
    for (int q = 0; q < 8; ++q) dst[q] = src[q];
  }
  __syncthreads();
  const int wv = tid >> 6, lane = tid & 63;
  const int ln31 = lane & 31, half = lane >> 5;
  const short8* bf = (const short8*)bfrag;
  #pragma unroll
  for (int nti = 0; nti < 2; ++nti) {
    const int ntg = wv + nti*4;
    short8 B[16];
    #pragma unroll
    for (int kt = 0; kt < 16; ++kt) B[kt] = bf[(ntg*16 + kt)*64 + lane];
    const float bv = bias[ntg*32 + ln31];
    #pragma unroll
    for (int mtl = 0; mtl < 2; ++mtl) {
      f32x16 acc;
      #pragma unroll
      for (int q = 0; q < 16; ++q) acc[q] = 0.f;
      const int base8 = (mtl*32 + ln31)*33 + half;
      #pragma unroll
      for (int kt = 0; kt < 16; ++kt) {
        const short8 a = ((const short8*)s_a)[base8 + kt*2];
        acc = MFMA_BF16(a, B[kt], acc, 0, 0, 0);
      }
      const int col = ntg*32 + ln31;
      #pragma unroll
      for (int r = 0; r < 16; ++r) {
        const long row = m0 + mtl*32 + rowfn(r, half);
        outbuf[row*256 + col] = bf16_rn(fmaxf(acc[r] + bv, 0.f));
      }
    }
  }
}

// ---------------- decoder GEMM 3: x_hat + recon loss + S_rw ----------------
__global__ __launch_bounds__(256) void dec3_kernel(
    const ushort_t* __restrict__ ain, const ushort_t* __restrict__ bfrag,
    const float* __restrict__ bias, const float* __restrict__ x,
    const float* __restrict__ tm, const float* __restrict__ imask,
    float* __restrict__ xhat, float* __restrict__ accums)
{
  __shared__ ushort_t s_a[64*264];
  const int tid = threadIdx.x;
  const long m0 = (long)blockIdx.x * 64;
  {
    const int row = tid >> 2, seg = tid & 3;
    const short8* src = (const short8*)(ain + (m0 + row)*256 + seg*64);
    short8* dst = (short8*)(s_a + row*264 + seg*64);
    #pragma unroll
    for (int q = 0; q < 8; ++q) dst[q] = src[q];
  }
  __syncthreads();
  const int wv = tid >> 6, lane = tid & 63;
  const int ln31 = lane & 31, half = lane >> 5;
  const short8* bf = (const short8*)bfrag;
  const int ntg = wv;
  short8 B[16];
  #pragma unroll
  for (int kt = 0; kt < 16; ++kt) B[kt] = bf[(ntg*16 + kt)*64 + lane];
  const int col = ntg*32 + ln31;
  const float bv = (col < 100) ? bias[col] : 0.f;
  float part = 0.f, wsum = 0.f;
  #pragma unroll
  for (int mtl = 0; mtl < 2; ++mtl) {
    f32x16 acc;
    #pragma unroll
    for (int q = 0; q < 16; ++q) acc[q] = 0.f;
    const int base8 = (mtl*32 + ln31)*33 + half;
    #pragma unroll
    for (int kt = 0; kt < 16; ++kt) {
      const short8 a = ((const short8*)s_a)[base8 + kt*2];
      acc = MFMA_BF16(a, B[kt], acc, 0, 0, 0);
    }
    if (col < 100) {
      #pragma unroll
      for (int r = 0; r < 16; ++r) {
        const long row = m0 + mtl*32 + rowfn(r, half);
        const float xh = acc[r] + bv;
        xhat[row*100 + col] = xh;
        const float wgt = imask[row] * tm[row*100 + col];
        const float df = xh - x[row*100 + col];
        part = fmaf(df*df, wgt, part);
        wsum += wgt;
      }
    }
  }
  #pragma unroll
  for (int off = 32; off > 0; off >>= 1) {
    part += __shfl_down(part, off); wsum += __shfl_down(wsum, off);
  }
  __shared__ float s_p[4], s_w[4];
  if (lane == 0) { s_p[wv] = part; s_w[wv] = wsum; }
  __syncthreads();
  if (tid == 0) {
    atomicAdd(&accums[0], s_p[0]+s_p[1]+s_p[2]+s_p[3]);
    atomicAdd(&accums[2], s_w[0]+s_w[1]+s_w[2]+s_w[3]);
  }
}

// ---------------- finalize scalars ----------------
__global__ void finalize_kernel(const float* __restrict__ accums, float* __restrict__ out) {
  if (threadIdx.x == 0 && blockIdx.x == 0) {
    out[5120000] = accums[0] / fmaxf(accums[2], 1.0f);
    out[5120001] = accums[1] / fmaxf(accums[3], 1.0f);
  }
}

extern "C" void kernel_launch(void* const* d_in, const int* in_sizes, int n_in,
                              void* d_out, int out_size, void* d_ws, size_t ws_size,
                              hipStream_t stream)
{
  (void)in_sizes; (void)n_in; (void)out_size; (void)ws_size;
  const float* x     = (const float*)d_in[0];
  const float* tmsk  = (const float*)d_in[1];
  const float* imask = (const float*)d_in[2];
  const float* w1    = (const float*)d_in[3];
  const float* b1    = (const float*)d_in[4];
  const float* w2    = (const float*)d_in[5];
  const float* b2    = (const float*)d_in[6];
  const float* latw  = (const float*)d_in[7];
  const float* latb  = (const float*)d_in[8];
  const float* cb    = (const float*)d_in[9];
  const float* d1w   = (const float*)d_in[10];
  const float* d1b   = (const float*)d_in[11];
  const float* d2w   = (const float*)d_in[12];
  const float* d2b   = (const float*)d_in[13];
  const float* d3w   = (const float*)d_in[14];
  const float* d3b   = (const float*)d_in[15];
  float* out = (float*)d_out;
  float* ws  = (float*)d_ws;

  float*    rnp0   = ws + WS_RNP0;
  float*    rnp1   = ws + WS_RNP1;
  ushort_t* zhi    = (ushort_t*)(ws + WS_ZHI);
  ushort_t* zlo    = (ushort_t*)(ws + WS_ZLO);
  ushort_t* ebhi   = (ushort_t*)(ws + WS_ENCBHI);
  ushort_t* eblo   = (ushort_t*)(ws + WS_ENCBLO);
  ushort_t* cbhi   = (ushort_t*)(ws + WS_CBHI);
  ushort_t* cblo   = (ushort_t*)(ws + WS_CBLO);
  float*    cbnorm = ws + WS_CBNORM;
  ushort_t* d1f    = (ushort_t*)(ws + WS_D1F);
  ushort_t* d2f    = (ushort_t*)(ws + WS_D2F);
  ushort_t* d3f    = (ushort_t*)(ws + WS_D3F);
  float*    accums = ws + WS_ACCUMS;
  u64*      gbest  = (u64*)(ws + WS_GBEST);
  ushort_t* h1     = (ushort_t*)(ws + WS_H1);
  ushort_t* h2     = (ushort_t*)(ws + WS_H2);
  float* xhat    = out;
  float* out_idx = out + 5120002;

  hipMemsetAsync(accums, 0, 8*sizeof(float), stream);

  prep_kernel<<<512, 256, 0, stream>>>(w2, cb, d1w, d2w, d3w,
                                       ebhi, eblo, cbhi, cblo, d1f, d2f, d3f, cbnorm);
  encoder_kernel<<<12800, 256, 0, stream>>>(x, tmsk, imask, w1, b1, ebhi, eblo, b2,
                                            latw, latb, zhi, zlo, rnp0, rnp1);
  vq_kernel<<<1600, 256, 0, stream>>>(zhi, zlo, cbhi, cblo, rnp0, rnp1, cbnorm, gbest);
  dec1_kernel<<<800, 256, 0, stream>>>(cb, gbest, imask, d1f, d1b, h1, out_idx, accums);
  dec2_kernel<<<800, 256, 0, stream>>>(h1, d2f, d2b, h2);
  dec3_kernel<<<800, 256, 0, stream>>>(h2, d3f, d3b, x, tmsk, imask, xhat, accums);
  finalize_kernel<<<1, 64, 0, stream>>>(accums, out);
}

// Round 6
// 479.767 us; speedup vs baseline: 1.3149x; 1.3149x over previous
//
#include <hip/hip_runtime.h>
#include <stdint.h>

typedef unsigned long long u64;
typedef unsigned short ushort_t;
typedef __attribute__((ext_vector_type(8))) short short8;
typedef __attribute__((ext_vector_type(8))) _Float16 half8;
typedef __attribute__((ext_vector_type(16))) float f32x16;

// Dims: B=512,N=100 -> M=51200; T=100, L=50 conv pos, HE=64, E=128, NE=512, HD=256.

// ---------------- workspace layout (float offsets) ----------------
#define WS_RNP0     0ll          // 51200 f32                          -> end    51,200
#define WS_RNP1     51200ll      // 51200 f32                          -> end   102,400
#define WS_ZHI      102400ll     // 51200*128 ushort = 3,276,800 f     -> end 3,379,200
#define WS_ZLO      3379200ll    // 3,276,800 f                        -> end 6,656,000
#define WS_ENCBHI   6656000ll    // 12288 ushort = 6144 f              -> end 6,662,144
#define WS_ENCBLO   6662144ll    // 6144 f                             -> end 6,668,288
#define WS_CBHI     6668288ll    // 65536 ushort = 32768 f             -> end 6,701,056
#define WS_CBLO     6701056ll    // 32768 f                            -> end 6,733,824
#define WS_CBNORM   6733824ll    // 512 f                              -> end 6,734,336
#define WS_D1F      6734336ll    // 32768 ushort = 16384 f             -> end 6,750,720
#define WS_D2F      6750720ll    // 65536 ushort = 32768 f             -> end 6,783,488
#define WS_D3F      6783488ll    // 32768 ushort = 16384 f             -> end 6,799,872
#define WS_ACCUMS   6799872ll    // 8 f32                              -> end 6,799,880
#define WS_GBEST    6799880ll    // 51200 u64 = 102,400 f (byte%8==0)  -> end 6,902,280
#define WS_H1       6902280ll    // 51200*256 ushort = 6,553,600 f     -> end 13,455,880
                                 // (red[51200*64] f32 = 3,276,800 f aliases H1 head;
                                 //  consumed by latent_kernel before dec1 writes h1)
#define WS_H2       13455880ll   // 6,553,600 f                        -> end 20,009,480 (~80 MB)

__device__ __host__ inline ushort_t bf16_rn(float v) {
  unsigned u = __float_as_uint(v);
  unsigned r = (u + 0x7fffu + ((u >> 16) & 1u)) >> 16;
  return (ushort_t)r;
}
union h2u { _Float16 h; unsigned short u; };
union s2h { short8 s; half8 h; };

// packed RNE f32x2 -> bf16x2 (v_cvt_pk_bf16_f32); low 16 bits = a, high = b.
__device__ inline unsigned pk2_bf16(float a, float b) {
  unsigned r;
  asm("v_cvt_pk_bf16_f32 %0, %1, %2" : "=v"(r) : "v"(a), "v"(b));
  return r;
}

__device__ inline int rowfn(int r, int half) { return (r & 3) + 8*(r >> 2) + 4*half; }

#define MFMA_BF16 __builtin_amdgcn_mfma_f32_32x32x16_bf16

// ---------------- prep: frag-pack all weights + codebook norms ----------------
__global__ __launch_bounds__(256) void prep_kernel(
    const float* __restrict__ w2, const float* __restrict__ cb,
    const float* __restrict__ d1w, const float* __restrict__ d2w,
    const float* __restrict__ d3w,
    ushort_t* __restrict__ ebhi, ushort_t* __restrict__ eblo,
    ushort_t* __restrict__ cbhi, ushort_t* __restrict__ cblo,
    ushort_t* __restrict__ d1f, ushort_t* __restrict__ d2f,
    ushort_t* __restrict__ d3f, float* __restrict__ cbnorm)
{
  const int total = 12288 + 65536 + 32768 + 65536 + 32768 + 512;
  for (int i = blockIdx.x*256 + threadIdx.x; i < total; i += gridDim.x*256) {
    int idx = i;
    if (idx < 12288) {
      // encoder conv2 B-frags (bf16 hi/lo), 32x32x16: f=((t*2+nt)*4+kt)
      int j = idx & 7, l6 = (idx >> 3) & 63, f = idx >> 9;
      int kt = f & 3, ntt = (f >> 2) & 1, t = f >> 3;
      int oc = ntt*32 + (l6 & 31);
      int ic = kt*16 + (l6 >> 5)*8 + j;
      float v = w2[(oc*64 + ic)*3 + t];
      ushort_t hi = bf16_rn(v);
      float hf = __uint_as_float(((unsigned)hi) << 16);
      ebhi[idx] = hi; eblo[idx] = bf16_rn(v - hf); continue;
    }
    idx -= 12288;
    if (idx < 65536) {
      // codebook f16 hi/lo frags, scaled x512: ntg16 x kt8
      int j = idx & 7, l6 = (idx >> 3) & 63, f = idx >> 9;
      int kt = f & 7, ntg = f >> 3;
      int k = kt*16 + (l6 >> 5)*8 + j;
      int n = ntg*32 + (l6 & 31);
      float v = cb[n*128 + k] * 512.0f;
      h2u a, b; a.h = (_Float16)v;
      b.h = (_Float16)(v - (float)a.h);
      cbhi[idx] = a.u; cblo[idx] = b.u; continue;
    }
    idx -= 65536;
    if (idx < 32768) {
      int j = idx & 7, l6 = (idx >> 3) & 63, f = idx >> 9;
      int kt = f & 7, ntg = f >> 3;
      int k = kt*16 + (l6 >> 5)*8 + j;
      int n = ntg*32 + (l6 & 31);
      d1f[idx] = bf16_rn(d1w[n*128 + k]); continue;
    }
    idx -= 32768;
    if (idx < 65536) {
      int j = idx & 7, l6 = (idx >> 3) & 63, f = idx >> 9;
      int kt = f & 15, ntg = f >> 4;
      int k = kt*16 + (l6 >> 5)*8 + j;
      int n = ntg*32 + (l6 & 31);
      d2f[idx] = bf16_rn(d2w[n*256 + k]); continue;
    }
    idx -= 65536;
    if (idx < 32768) {
      int j = idx & 7, l6 = (idx >> 3) & 63, f = idx >> 9;
      int kt = f & 15, ntg = f >> 4;
      int k = kt*16 + (l6 >> 5)*8 + j;
      int n = ntg*32 + (l6 & 31);
      d3f[idx] = (n < 100) ? bf16_rn(d3w[n*256 + k]) : (ushort_t)0; continue;
    }
    idx -= 32768;
    { double s = 0.0; const float* c = cb + idx*128;
      for (int e = 0; e < 128; ++e) { double v = (double)c[e]; s += v*v; }
      cbnorm[idx] = (float)s; }
  }
}

// ---------------- encoder v5: one wave per m, zero barriers, 3 blocks/CU ----------------
// Per-wave H slice: 52 rows x 256B (hi 64 ush | lo 64 ush), XOR-swizzled
// byte ^= (row&7)<<4 within each row (T2) to break the power-of-2 stride conflict.
// Rows 0 and 51 are zero halos (zeros are swizzle-invariant). LDS = 53,248 B/block
// -> exactly 3 blocks/CU (159,744 <= 163,840). Latent phase moved to latent_kernel;
// epilogue writes red[m][64] f32. No __syncthreads; intra-wave fence only.
__global__ __launch_bounds__(256, 3) void encoder_kernel(
    const float* __restrict__ x, const float* __restrict__ tm,
    const float* __restrict__ imask,
    const float* w1, const float* b1,
    const ushort_t* __restrict__ ebhi, const ushort_t* __restrict__ eblo,
    const float* b2, float* __restrict__ red)
{
  __shared__ ushort_t s_H[4][52*128];   // 53,248 B total
  const int tid  = threadIdx.x;
  const int wv   = __builtin_amdgcn_readfirstlane((int)(tid >> 6));
  const int lane = tid & 63;
  const int ln31 = lane & 31, half = lane >> 5;
  const long m   = (long)blockIdx.x*4 + wv;     // wave-uniform
  const float imv = imask[m];                   // scalar load
  ushort_t* Hw  = s_H[wv];

  // ---- conv1: inputs straight from global (3 float2 pairs per lane) ----
  {
    const int p = (lane < 50) ? lane : 0;
    const long xb = m*100 + 2*p;
    const float2 x0v = *(const float2*)(x + xb);
    const float2 t0v = *(const float2*)(tm + xb);
    float2 xmv = {0.f, 0.f}, tmv = {0.f, 0.f};
    float2 xpv = {0.f, 0.f}, tpv = {0.f, 0.f};
    if (p > 0)  { xmv = *(const float2*)(x + xb - 2); tmv = *(const float2*)(tm + xb - 2); }
    if (p < 49) { xpv = *(const float2*)(x + xb + 2); tpv = *(const float2*)(tm + xb + 2); }
    const float a0 = xmv.x*tmv.x, c0 = xmv.y*tmv.y;
    const float a1 = x0v.x*t0v.x, c1 = x0v.y*t0v.y;
    const float a2 = xpv.x*tpv.x, c2 = xpv.y*tpv.y;
    const int row = lane + 1;                    // H row = pos+1
    const int sw  = (row & 7) << 4;              // XOR swizzle within 256B row
    char* rbase = (char*)(Hw + row*128);
    #pragma unroll
    for (int g = 0; g < 4; ++g) {
      unsigned hi8[8], lo8[8];
      #pragma unroll
      for (int pr = 0; pr < 8; ++pr) {
        const int o = g*16 + pr*2;
        const float* wA = w1 + (long)o*6;       // wave-uniform -> s_load
        const float* wB = wA + 6;
        float sA = 0.f, sB = 0.f;
        sA = fmaf(wA[0], a0, sA); sA = fmaf(wA[1], a1, sA); sA = fmaf(wA[2], a2, sA);
        sA = fmaf(wA[3], c0, sA); sA = fmaf(wA[4], c1, sA); sA = fmaf(wA[5], c2, sA);
        sB = fmaf(wB[0], a0, sB); sB = fmaf(wB[1], a1, sB); sB = fmaf(wB[2], a2, sB);
        sB = fmaf(wB[3], c0, sB); sB = fmaf(wB[4], c1, sB); sB = fmaf(wB[5], c2, sB);
        const float hA = fmaxf(fmaf(imv, sA, b1[o]),     0.f);
        const float hB = fmaxf(fmaf(imv, sB, b1[o + 1]), 0.f);
        const unsigned h = pk2_bf16(hA, hB);
        const float ha = __uint_as_float(h << 16);
        const float hb = __uint_as_float(h & 0xffff0000u);
        lo8[pr] = pk2_bf16(hA - ha, hB - hb);
        hi8[pr] = h;
      }
      if (lane < 50) {
        *(short8*)(rbase + ((g*32)       ^ sw)) = *(short8*)&hi8[0];
        *(short8*)(rbase + ((g*32 + 16)  ^ sw)) = *(short8*)&hi8[4];
        *(short8*)(rbase + (128 + ((g*32)      ^ sw))) = *(short8*)&lo8[0];
        *(short8*)(rbase + (128 + ((g*32 + 16) ^ sw))) = *(short8*)&lo8[4];
      }
    }
    if (lane == 50 || lane == 51) {          // zero halo rows 0 and 51 (swizzle-invariant)
      const int zr = (lane == 50) ? 0 : 51;
      short8 z8 = {};
      short8* d = (short8*)(Hw + zr*128);
      #pragma unroll
      for (int i = 0; i < 16; ++i) d[i] = z8;
    }
  }
  // intra-wave LDS write->read fence (wave-private slice; no barrier)
  asm volatile("s_waitcnt lgkmcnt(0)" ::: "memory");
  __builtin_amdgcn_sched_barrier(0);

  // ---- conv2 MFMA: all 4 (mt,nt) tiles of this wave's m ----
  f32x16 acc00, acc01, acc10, acc11;
  #pragma unroll
  for (int q = 0; q < 16; ++q) { acc00[q] = 0.f; acc01[q] = 0.f; acc10[q] = 0.f; acc11[q] = 0.f; }
  {
    const short8* bh8 = (const short8*)ebhi;
    const short8* bl8 = (const short8*)eblo;
    for (int t = 0; t < 3; ++t) {
      const int r0 = ln31 + t;                // 0..33, valid
      int r1 = 32 + ln31 + t;                 // 32..65 -> clamp to zero halo 51
      if (r1 > 51) r1 = 51;
      const int sw0 = (r0 & 7) << 4, sw1 = (r1 & 7) << 4;
      const char* b0p = (const char*)(Hw + r0*128);
      const char* b1p = (const char*)(Hw + r1*128);
      #pragma unroll
      for (int kt = 0; kt < 4; ++kt) {
        const int f0 = (t*2 + 0)*4 + kt;
        const int f1 = (t*2 + 1)*4 + kt;
        const int offh = kt*32 + half*16;
        const short8 Bh0 = bh8[f0*64 + lane], Bl0 = bl8[f0*64 + lane];
        const short8 Bh1 = bh8[f1*64 + lane], Bl1 = bl8[f1*64 + lane];
        const short8 ah0 = *(const short8*)(b0p + (offh ^ sw0));
        const short8 al0 = *(const short8*)(b0p + (128 + (offh ^ sw0)));
        const short8 ah1 = *(const short8*)(b1p + (offh ^ sw1));
        const short8 al1 = *(const short8*)(b1p + (128 + (offh ^ sw1)));
        acc00 = MFMA_BF16(ah0, Bh0, acc00, 0, 0, 0);
        acc00 = MFMA_BF16(ah0, Bl0, acc00, 0, 0, 0);
        acc00 = MFMA_BF16(al0, Bh0, acc00, 0, 0, 0);
        acc01 = MFMA_BF16(ah0, Bh1, acc01, 0, 0, 0);
        acc01 = MFMA_BF16(ah0, Bl1, acc01, 0, 0, 0);
        acc01 = MFMA_BF16(al0, Bh1, acc01, 0, 0, 0);
        acc10 = MFMA_BF16(ah1, Bh0, acc10, 0, 0, 0);
        acc10 = MFMA_BF16(ah1, Bl0, acc10, 0, 0, 0);
        acc10 = MFMA_BF16(al1, Bh0, acc10, 0, 0, 0);
        acc11 = MFMA_BF16(ah1, Bh1, acc11, 0, 0, 0);
        acc11 = MFMA_BF16(ah1, Bl1, acc11, 0, 0, 0);
        acc11 = MFMA_BF16(al1, Bh1, acc11, 0, 0, 0);
      }
    }
  }

  // ---- relu + bias + masked position-sum -> red[m][64] (f32, global) ----
  {
    const float bv0 = b2[ln31];
    const float bv1 = b2[32 + ln31];
    float s0 = 0.f, s1 = 0.f;
    #pragma unroll
    for (int r = 0; r < 16; ++r) {
      s0 += fmaxf(acc00[r] + bv0, 0.f);              // mt=0: pos 0..31 all valid
      s1 += fmaxf(acc01[r] + bv1, 0.f);
      const int mpos = 32 + rowfn(r, half);          // mt=1: keep pos<50
      const float v10 = fmaxf(acc10[r] + bv0, 0.f);
      const float v11 = fmaxf(acc11[r] + bv1, 0.f);
      if (mpos < 50) { s0 += v10; s1 += v11; }
    }
    s0 += __shfl_xor(s0, 32);
    s1 += __shfl_xor(s1, 32);
    if (half == 0) {
      red[m*64 + ln31]      = s0;
      red[m*64 + 32 + ln31] = s1;
    }
  }
}

// ---------------- latent: z = (latb + 0.02 * red @ latw^T) * im, f32 VALU ----------------
// Block = 64 m; red staged in LDS (16KB); thread = (e = tid&127, mh = tid>>7),
// holds latw row e in 64 VGPRs (latw traffic 1.6GB -> 26MB), loops 32 m.
__global__ __launch_bounds__(256, 4) void latent_kernel(
    const float* __restrict__ red, const float* __restrict__ imask,
    const float* __restrict__ latw, const float* __restrict__ latb,
    ushort_t* __restrict__ zhi, ushort_t* __restrict__ zlo,
    float* __restrict__ rnp0, float* __restrict__ rnp1)
{
  __shared__ float s_r[64*64];
  __shared__ float s_im[64];
  const int tid = threadIdx.x;
  const long m0 = (long)blockIdx.x * 64;
  {
    const int r = tid >> 2, seg = tid & 3;
    const float4* src = (const float4*)(red + (m0 + r)*64 + seg*16);
    float4* dst = (float4*)(s_r + r*64 + seg*16);
    dst[0] = src[0]; dst[1] = src[1]; dst[2] = src[2]; dst[3] = src[3];
  }
  if (tid < 64) s_im[tid] = imask[m0 + tid];
  __syncthreads();

  const int e = tid & 127, mh = tid >> 7;
  const int lane = tid & 63;
  float4 W[16];
  const float4* wp = (const float4*)(latw + (long)e*64);
  #pragma unroll
  for (int q = 0; q < 16; ++q) W[q] = wp[q];
  const float lb = latb[e];

  for (int i = 0; i < 32; ++i) {
    const int ml = mh*32 + i;                         // wave-uniform
    const float4* rp = (const float4*)(s_r + ml*64);  // LDS broadcast
    float a = 0.f;
    #pragma unroll
    for (int q = 0; q < 16; ++q) {
      const float4 r4 = rp[q];
      a = fmaf(W[q].x, r4.x, a); a = fmaf(W[q].y, r4.y, a);
      a = fmaf(W[q].z, r4.z, a); a = fmaf(W[q].w, r4.w, a);
    }
    const float z = fmaf(0.02f, a, lb) * s_im[ml];
    h2u zh, zl; zh.h = (_Float16)z; zl.h = (_Float16)(z - (float)zh.h);
    const long mg = m0 + ml;
    zhi[mg*128 + e] = zh.u;
    zlo[mg*128 + e] = zl.u;
    float v = z*z;
    #pragma unroll
    for (int off = 32; off > 0; off >>= 1) v += __shfl_down(v, off);
    if (lane == 0) { if (e < 64) rnp0[mg] = v; else rnp1[mg] = v; }
  }
}

// ---------------- VQ: f16 3-pass MFMA, 32 rows x all 512 codes per block ----------------
__global__ __launch_bounds__(256) void vq_kernel(
    const ushort_t* __restrict__ zhi, const ushort_t* __restrict__ zlo,
    const ushort_t* __restrict__ cbhi, const ushort_t* __restrict__ cblo,
    const float* __restrict__ rnp0, const float* __restrict__ rnp1,
    const float* __restrict__ cbnorm, u64* __restrict__ gbest)
{
  __shared__ ushort_t s_ah[32*136];
  __shared__ ushort_t s_al[32*136];
  __shared__ float s_rn[32];
  __shared__ u64 s_best[32];
  const int tid = threadIdx.x;
  const int m0 = blockIdx.x * 32;
  {
    const short8* gh = (const short8*)(zhi + (long)m0*128);
    const short8* gl = (const short8*)(zlo + (long)m0*128);
    const int row = tid >> 3, c8 = (tid & 7)*2;
    ((short8*)s_ah)[row*17 + c8]     = gh[tid*2];
    ((short8*)s_ah)[row*17 + c8 + 1] = gh[tid*2 + 1];
    ((short8*)s_al)[row*17 + c8]     = gl[tid*2];
    ((short8*)s_al)[row*17 + c8 + 1] = gl[tid*2 + 1];
  }
  if (tid < 32) { s_rn[tid] = rnp0[m0 + tid] + rnp1[m0 + tid]; s_best[tid] = ~0ULL; }
  __syncthreads();

  const int wv = tid >> 6, lane = tid & 63;
  const int ln31 = lane & 31, half = lane >> 5;
  float rnv[16];
  #pragma unroll
  for (int r = 0; r < 16; ++r) rnv[r] = s_rn[rowfn(r, half)];

  u64 best[16];
  #pragma unroll
  for (int r = 0; r < 16; ++r) best[r] = ~0ULL;

  const short8* ch8 = (const short8*)cbhi;
  const short8* cl8 = (const short8*)cblo;
  for (int ct = 0; ct < 4; ++ct) {
    const int ntg = wv*4 + ct;
    half8 Bh[8], Bl[8];
    #pragma unroll
    for (int kt = 0; kt < 8; ++kt) {
      s2h a, b;
      a.s = ch8[(ntg*8 + kt)*64 + lane];
      b.s = cl8[(ntg*8 + kt)*64 + lane];
      Bh[kt] = a.h; Bl[kt] = b.h;
    }
    f32x16 acc;
    #pragma unroll
    for (int q = 0; q < 16; ++q) acc[q] = 0.f;
    const int base8 = ln31*17 + half;
    #pragma unroll
    for (int kt = 0; kt < 8; ++kt) {
      s2h ah, al;
      ah.s = ((const short8*)s_ah)[base8 + kt*2];
      al.s = ((const short8*)s_al)[base8 + kt*2];
      acc = __builtin_amdgcn_mfma_f32_32x32x16_f16(ah.h, Bh[kt], acc, 0, 0, 0);
      acc = __builtin_amdgcn_mfma_f32_32x32x16_f16(ah.h, Bl[kt], acc, 0, 0, 0);
      acc = __builtin_amdgcn_mfma_f32_32x32x16_f16(al.h, Bh[kt], acc, 0, 0, 0);
    }
    const int code = ntg*32 + ln31;
    const float nrm = cbnorm[code];
    #pragma unroll
    for (int r = 0; r < 16; ++r) {
      const float t = fmaf(-0.00390625f, acc[r], rnv[r]);  // A - p/256 (cb scaled x512)
      const float d = t + nrm;
      const u64 pk = ((u64)__float_as_uint(d) << 32) | (u64)(unsigned)code;
      if (pk < best[r]) best[r] = pk;
    }
  }
  #pragma unroll
  for (int r = 0; r < 16; ++r) atomicMin(&s_best[rowfn(r, half)], best[r]);
  __syncthreads();
  if (tid < 32) gbest[m0 + tid] = s_best[tid];
}

// ---------------- decoder GEMM 1 + fused indices/vq-loss/S_im ----------------
__global__ __launch_bounds__(256) void dec1_kernel(
    const float* __restrict__ cb, const u64* __restrict__ gbest,
    const float* __restrict__ imask, const ushort_t* __restrict__ bfrag,
    const float* __restrict__ bias, ushort_t* __restrict__ h1out,
    float* __restrict__ out_idx, float* __restrict__ accums)
{
  __shared__ ushort_t s_a[64*136];
  __shared__ int s_idx[64];
  __shared__ float s_act[64];
  const int tid = threadIdx.x;
  const long m0 = (long)blockIdx.x * 64;
  if (tid < 64) {
    const u64 pk = gbest[m0 + tid];
    const int ii = (int)(unsigned)(pk & 0xffffffffULL);
    const float dd = __uint_as_float((unsigned)(pk >> 32));
    const float imv = imask[m0 + tid];
    s_idx[tid] = ii; s_act[tid] = imv;
    out_idx[m0 + tid] = (imv > 0.f) ? (float)ii : -1.0f;
    float vqp = 1.25f * dd * (1.0f/128.0f) * imv;
    float sim = imv;
    #pragma unroll
    for (int off = 32; off > 0; off >>= 1) {
      vqp += __shfl_down(vqp, off); sim += __shfl_down(sim, off);
    }
    if (tid == 0) { atomicAdd(&accums[1], vqp); atomicAdd(&accums[3], sim); }
  }
  __syncthreads();
  {
    const int row = tid >> 2, seg = tid & 3;
    const float4* src = (const float4*)(cb + (long)s_idx[row]*128 + seg*32);
    const float im = s_act[row];
    ushort_t tmp[32];
    #pragma unroll
    for (int q = 0; q < 8; ++q) {
      const float4 v = src[q];
      tmp[q*4+0] = bf16_rn(v.x*im); tmp[q*4+1] = bf16_rn(v.y*im);
      tmp[q*4+2] = bf16_rn(v.z*im); tmp[q*4+3] = bf16_rn(v.w*im);
    }
    short8* dst = (short8*)(s_a + row*136 + seg*32);
    #pragma unroll
    for (int q = 0; q < 4; ++q) dst[q] = *(short8*)&tmp[q*8];
  }
  __syncthreads();
  const int wv = tid >> 6, lane = tid & 63;
  const int ln31 = lane & 31, half = lane >> 5;
  const short8* bf = (const short8*)bfrag;
  #pragma unroll
  for (int nti = 0; nti < 2; ++nti) {
    const int ntg = wv + nti*4;
    short8 B[8];
    #pragma unroll
    for (int kt = 0; kt < 8; ++kt) B[kt] = bf[(ntg*8 + kt)*64 + lane];
    const float bv = bias[ntg*32 + ln31];
    #pragma unroll
    for (int mtl = 0; mtl < 2; ++mtl) {
      f32x16 acc;
      #pragma unroll
      for (int q = 0; q < 16; ++q) acc[q] = 0.f;
      const int base8 = (mtl*32 + ln31)*17 + half;
      #pragma unroll
      for (int kt = 0; kt < 8; ++kt) {
        const short8 a = ((const short8*)s_a)[base8 + kt*2];
        acc = MFMA_BF16(a, B[kt], acc, 0, 0, 0);
      }
      const int col = ntg*32 + ln31;
      #pragma unroll
      for (int r = 0; r < 16; ++r) {
        const long row = m0 + mtl*32 + rowfn(r, half);
        h1out[row*256 + col] = bf16_rn(fmaxf(acc[r] + bv, 0.f));
      }
    }
  }
}

// ---------------- decoder GEMM 2: h2 = relu(h1 @ d2^T + b), K=256 ----------------
__global__ __launch_bounds__(256) void dec2_kernel(
    const ushort_t* __restrict__ ain, const ushort_t* __restrict__ bfrag,
    const float* __restrict__ bias, ushort_t* __restrict__ outbuf)
{
  __shared__ ushort_t s_a[64*264];
  const int tid = threadIdx.x;
  const long m0 = (long)blockIdx.x * 64;
  {
    const int row = tid >> 2, seg = tid & 3;
    const short8* src = (const short8*)(ain + (m0 + row)*256 + seg*64);
    short8* dst = (short8*)(s_a + row*264 + seg*64);
    #pragma unroll
    for (int q = 0; q < 8; ++q) dst[q] = src[q];
  }
  __syncthreads();
  const int wv = tid >> 6, lane = tid & 63;
  const int ln31 = lane & 31, half = lane >> 5;
  const short8* bf = (const short8*)bfrag;
  #pragma unroll
  for (int nti = 0; nti < 2; ++nti) {
    const int ntg = wv + nti*4;
    short8 B[16];
    #pragma unroll
    for (int kt = 0; kt < 16; ++kt) B[kt] = bf[(ntg*16 + kt)*64 + lane];
    const float bv = bias[ntg*32 + ln31];
    #pragma unroll
    for (int mtl = 0; mtl < 2; ++mtl) {
      f32x16 acc;
      #pragma unroll
      for (int q = 0; q < 16; ++q) acc[q] = 0.f;
      const int base8 = (mtl*32 + ln31)*33 + half;
      #pragma unroll
      for (int kt = 0; kt < 16; ++kt) {
        const short8 a = ((const short8*)s_a)[base8 + kt*2];
        acc = MFMA_BF16(a, B[kt], acc, 0, 0, 0);
      }
      const int col = ntg*32 + ln31;
      #pragma unroll
      for (int r = 0; r < 16; ++r) {
        const long row = m0 + mtl*32 + rowfn(r, half);
        outbuf[row*256 + col] = bf16_rn(fmaxf(acc[r] + bv, 0.f));
      }
    }
  }
}

// ---------------- decoder GEMM 3: x_hat + recon loss + S_rw ----------------
__global__ __launch_bounds__(256) void dec3_kernel(
    const ushort_t* __restrict__ ain, const ushort_t* __restrict__ bfrag,
    const float* __restrict__ bias, const float* __restrict__ x,
    const float* __restrict__ tm, const float* __restrict__ imask,
    float* __restrict__ xhat, float* __restrict__ accums)
{
  __shared__ ushort_t s_a[64*264];
  const int tid = threadIdx.x;
  const long m0 = (long)blockIdx.x * 64;
  {
    const int row = tid >> 2, seg = tid & 3;
    const short8* src = (const short8*)(ain + (m0 + row)*256 + seg*64);
    short8* dst = (short8*)(s_a + row*264 + seg*64);
    #pragma unroll
    for (int q = 0; q < 8; ++q) dst[q] = src[q];
  }
  __syncthreads();
  const int wv = tid >> 6, lane = tid & 63;
  const int ln31 = lane & 31, half = lane >> 5;
  const short8* bf = (const short8*)bfrag;
  const int ntg = wv;
  short8 B[16];
  #pragma unroll
  for (int kt = 0; kt < 16; ++kt) B[kt] = bf[(ntg*16 + kt)*64 + lane];
  const int col = ntg*32 + ln31;
  const float bv = (col < 100) ? bias[col] : 0.f;
  float part = 0.f, wsum = 0.f;
  #pragma unroll
  for (int mtl = 0; mtl < 2; ++mtl) {
    f32x16 acc;
    #pragma unroll
    for (int q = 0; q < 16; ++q) acc[q] = 0.f;
    const int base8 = (mtl*32 + ln31)*33 + half;
    #pragma unroll
    for (int kt = 0; kt < 16; ++kt) {
      const short8 a = ((const short8*)s_a)[base8 + kt*2];
      acc = MFMA_BF16(a, B[kt], acc, 0, 0, 0);
    }
    if (col < 100) {
      #pragma unroll
      for (int r = 0; r < 16; ++r) {
        const long row = m0 + mtl*32 + rowfn(r, half);
        const float xh = acc[r] + bv;
        xhat[row*100 + col] = xh;
        const float wgt = imask[row] * tm[row*100 + col];
        const float df = xh - x[row*100 + col];
        part = fmaf(df*df, wgt, part);
        wsum += wgt;
      }
    }
  }
  #pragma unroll
  for (int off = 32; off > 0; off >>= 1) {
    part += __shfl_down(part, off); wsum += __shfl_down(wsum, off);
  }
  __shared__ float s_p[4], s_w[4];
  if (lane == 0) { s_p[wv] = part; s_w[wv] = wsum; }
  __syncthreads();
  if (tid == 0) {
    atomicAdd(&accums[0], s_p[0]+s_p[1]+s_p[2]+s_p[3]);
    atomicAdd(&accums[2], s_w[0]+s_w[1]+s_w[2]+s_w[3]);
  }
}

// ---------------- finalize scalars ----------------
__global__ void finalize_kernel(const float* __restrict__ accums, float* __restrict__ out) {
  if (threadIdx.x == 0 && blockIdx.x == 0) {
    out[5120000] = accums[0] / fmaxf(accums[2], 1.0f);
    out[5120001] = accums[1] / fmaxf(accums[3], 1.0f);
  }
}

extern "C" void kernel_launch(void* const* d_in, const int* in_sizes, int n_in,
                              void* d_out, int out_size, void* d_ws, size_t ws_size,
                              hipStream_t stream)
{
  (void)in_sizes; (void)n_in; (void)out_size; (void)ws_size;
  const float* x     = (const float*)d_in[0];
  const float* tmsk  = (const float*)d_in[1];
  const float* imask = (const float*)d_in[2];
  const float* w1    = (const float*)d_in[3];
  const float* b1    = (const float*)d_in[4];
  const float* w2    = (const float*)d_in[5];
  const float* b2    = (const float*)d_in[6];
  const float* latw  = (const float*)d_in[7];
  const float* latb  = (const float*)d_in[8];
  const float* cb    = (const float*)d_in[9];
  const float* d1w   = (const float*)d_in[10];
  const float* d1b   = (const float*)d_in[11];
  const float* d2w   = (const float*)d_in[12];
  const float* d2b   = (const float*)d_in[13];
  const float* d3w   = (const float*)d_in[14];
  const float* d3b   = (const float*)d_in[15];
  float* out = (float*)d_out;
  float* ws  = (float*)d_ws;

  float*    rnp0   = ws + WS_RNP0;
  float*    rnp1   = ws + WS_RNP1;
  ushort_t* zhi    = (ushort_t*)(ws + WS_ZHI);
  ushort_t* zlo    = (ushort_t*)(ws + WS_ZLO);
  ushort_t* ebhi   = (ushort_t*)(ws + WS_ENCBHI);
  ushort_t* eblo   = (ushort_t*)(ws + WS_ENCBLO);
  ushort_t* cbhi   = (ushort_t*)(ws + WS_CBHI);
  ushort_t* cblo   = (ushort_t*)(ws + WS_CBLO);
  float*    cbnorm = ws + WS_CBNORM;
  ushort_t* d1f    = (ushort_t*)(ws + WS_D1F);
  ushort_t* d2f    = (ushort_t*)(ws + WS_D2F);
  ushort_t* d3f    = (ushort_t*)(ws + WS_D3F);
  float*    accums = ws + WS_ACCUMS;
  u64*      gbest  = (u64*)(ws + WS_GBEST);
  ushort_t* h1     = (ushort_t*)(ws + WS_H1);
  ushort_t* h2     = (ushort_t*)(ws + WS_H2);
  float*    red    = ws + WS_H1;      // aliases h1 head; consumed before dec1 writes h1
  float* xhat    = out;
  float* out_idx = out + 5120002;

  hipMemsetAsync(accums, 0, 8*sizeof(float), stream);

  prep_kernel<<<512, 256, 0, stream>>>(w2, cb, d1w, d2w, d3w,
                                       ebhi, eblo, cbhi, cblo, d1f, d2f, d3f, cbnorm);
  encoder_kernel<<<12800, 256, 0, stream>>>(x, tmsk, imask, w1, b1, ebhi, eblo, b2, red);
  latent_kernel<<<800, 256, 0, stream>>>(red, imask, latw, latb, zhi, zlo, rnp0, rnp1);
  vq_kernel<<<1600, 256, 0, stream>>>(zhi, zlo, cbhi, cblo, rnp0, rnp1, cbnorm, gbest);
  dec1_kernel<<<800, 256, 0, stream>>>(cb, gbest, imask, d1f, d1b, h1, out_idx, accums);
  dec2_kernel<<<800, 256, 0, stream>>>(h1, d2f, d2b, h2);
  dec3_kernel<<<800, 256, 0, stream>>>(h2, d3f, d3b, x, tmsk, imask, xhat, accums);
  finalize_kernel<<<1, 64, 0, stream>>>(accums, out);
}

// Round 7
// 436.989 us; speedup vs baseline: 1.4436x; 1.0979x over previous
//
#include <hip/hip_runtime.h>
#include <stdint.h>

typedef unsigned long long u64;
typedef unsigned short ushort_t;
typedef __attribute__((ext_vector_type(8))) short short8;
typedef __attribute__((ext_vector_type(8))) _Float16 half8;
typedef __attribute__((ext_vector_type(16))) float f32x16;

// Dims: B=512,N=100 -> M=51200; T=100, L=50 conv pos, HE=64, E=128, NE=512, HD=256.

// ---------------- workspace layout (float offsets) ----------------
#define WS_RNP0     0ll          // 51200 f32                          -> end    51,200
#define WS_RNP1     51200ll      // 51200 f32                          -> end   102,400
#define WS_ZHI      102400ll     // 51200*128 ushort = 3,276,800 f     -> end 3,379,200
#define WS_ZLO      3379200ll    // 3,276,800 f                        -> end 6,656,000
#define WS_ENCBHI   6656000ll    // 12288 ushort = 6144 f              -> end 6,662,144
#define WS_ENCBLO   6662144ll    // 6144 f                             -> end 6,668,288
#define WS_CBHI     6668288ll    // 65536 ushort = 32768 f             -> end 6,701,056
#define WS_CBLO     6701056ll    // 32768 f                            -> end 6,733,824
#define WS_CBNORM   6733824ll    // 512 f                              -> end 6,734,336
#define WS_D1F      6734336ll    // 32768 ushort = 16384 f             -> end 6,750,720
#define WS_D2F      6750720ll    // 65536 ushort = 32768 f             -> end 6,783,488
#define WS_D3F      6783488ll    // 32768 ushort = 16384 f             -> end 6,799,872
#define WS_ACCUMS   6799872ll    // 8 f32                              -> end 6,799,880
#define WS_GBEST    6799880ll    // 51200 u64 = 102,400 f (byte%8==0)  -> end 6,902,280
#define WS_RED      6902280ll    // red[51200*64] f32 = 3,276,800 f    -> end 10,179,080

__device__ __host__ inline ushort_t bf16_rn(float v) {
  unsigned u = __float_as_uint(v);
  unsigned r = (u + 0x7fffu + ((u >> 16) & 1u)) >> 16;
  return (ushort_t)r;
}
union h2u { _Float16 h; unsigned short u; };
union s2h { short8 s; half8 h; };

// packed RNE f32x2 -> bf16x2 (v_cvt_pk_bf16_f32); low 16 bits = a, high = b.
__device__ inline unsigned pk2_bf16(float a, float b) {
  unsigned r;
  asm("v_cvt_pk_bf16_f32 %0, %1, %2" : "=v"(r) : "v"(a), "v"(b));
  return r;
}

__device__ inline int rowfn(int r, int half) { return (r & 3) + 8*(r >> 2) + 4*half; }

#define MFMA_BF16 __builtin_amdgcn_mfma_f32_32x32x16_bf16

// ---------------- prep: frag-pack all weights + codebook norms ----------------
__global__ __launch_bounds__(256) void prep_kernel(
    const float* __restrict__ w2, const float* __restrict__ cb,
    const float* __restrict__ d1w, const float* __restrict__ d2w,
    const float* __restrict__ d3w,
    ushort_t* __restrict__ ebhi, ushort_t* __restrict__ eblo,
    ushort_t* __restrict__ cbhi, ushort_t* __restrict__ cblo,
    ushort_t* __restrict__ d1f, ushort_t* __restrict__ d2f,
    ushort_t* __restrict__ d3f, float* __restrict__ cbnorm)
{
  const int total = 12288 + 65536 + 32768 + 65536 + 32768 + 512;
  for (int i = blockIdx.x*256 + threadIdx.x; i < total; i += gridDim.x*256) {
    int idx = i;
    if (idx < 12288) {
      // encoder conv2 B-frags (bf16 hi/lo), 32x32x16: f=((t*2+nt)*4+kt)
      int j = idx & 7, l6 = (idx >> 3) & 63, f = idx >> 9;
      int kt = f & 3, ntt = (f >> 2) & 1, t = f >> 3;
      int oc = ntt*32 + (l6 & 31);
      int ic = kt*16 + (l6 >> 5)*8 + j;
      float v = w2[(oc*64 + ic)*3 + t];
      ushort_t hi = bf16_rn(v);
      float hf = __uint_as_float(((unsigned)hi) << 16);
      ebhi[idx] = hi; eblo[idx] = bf16_rn(v - hf); continue;
    }
    idx -= 12288;
    if (idx < 65536) {
      // codebook f16 hi/lo frags, scaled x512: ntg16 x kt8
      int j = idx & 7, l6 = (idx >> 3) & 63, f = idx >> 9;
      int kt = f & 7, ntg = f >> 3;
      int k = kt*16 + (l6 >> 5)*8 + j;
      int n = ntg*32 + (l6 & 31);
      float v = cb[n*128 + k] * 512.0f;
      h2u a, b; a.h = (_Float16)v;
      b.h = (_Float16)(v - (float)a.h);
      cbhi[idx] = a.u; cblo[idx] = b.u; continue;
    }
    idx -= 65536;
    if (idx < 32768) {
      int j = idx & 7, l6 = (idx >> 3) & 63, f = idx >> 9;
      int kt = f & 7, ntg = f >> 3;
      int k = kt*16 + (l6 >> 5)*8 + j;
      int n = ntg*32 + (l6 & 31);
      d1f[idx] = bf16_rn(d1w[n*128 + k]); continue;
    }
    idx -= 32768;
    if (idx < 65536) {
      int j = idx & 7, l6 = (idx >> 3) & 63, f = idx >> 9;
      int kt = f & 15, ntg = f >> 4;
      int k = kt*16 + (l6 >> 5)*8 + j;
      int n = ntg*32 + (l6 & 31);
      d2f[idx] = bf16_rn(d2w[n*256 + k]); continue;
    }
    idx -= 65536;
    if (idx < 32768) {
      int j = idx & 7, l6 = (idx >> 3) & 63, f = idx >> 9;
      int kt = f & 15, ntg = f >> 4;
      int k = kt*16 + (l6 >> 5)*8 + j;
      int n = ntg*32 + (l6 & 31);
      d3f[idx] = (n < 100) ? bf16_rn(d3w[n*256 + k]) : (ushort_t)0; continue;
    }
    idx -= 32768;
    { double s = 0.0; const float* c = cb + idx*128;
      for (int e = 0; e < 128; ++e) { double v = (double)c[e]; s += v*v; }
      cbnorm[idx] = (float)s; }
  }
}

// ---------------- encoder v6: one wave per m, zero barriers, 3 blocks/CU ----------------
// Per-wave H slice: 52 rows x 256B (hi | lo planes), 16-slot XOR swizzle
// sw = ((row&7)<<4) | (((row>>3)&1)<<7): 32 consecutive rows -> 16 distinct slots
// (read 2-way = free, write ~3-way). Zero halo rows 0/51 swizzle-invariant.
// LDS 53,248 B -> exactly 3 blocks/CU. No __syncthreads; intra-wave fence only.
__global__ __launch_bounds__(256, 3) void encoder_kernel(
    const float* __restrict__ x, const float* __restrict__ tm,
    const float* __restrict__ imask,
    const float* w1, const float* b1,
    const ushort_t* __restrict__ ebhi, const ushort_t* __restrict__ eblo,
    const float* b2, float* __restrict__ red)
{
  __shared__ ushort_t s_H[4][52*128];   // 53,248 B total
  const int tid  = threadIdx.x;
  const int wv   = __builtin_amdgcn_readfirstlane((int)(tid >> 6));
  const int lane = tid & 63;
  const int ln31 = lane & 31, half = lane >> 5;
  const long m   = (long)blockIdx.x*4 + wv;     // wave-uniform
  const float imv = imask[m];                   // scalar load
  ushort_t* Hw  = s_H[wv];

  // ---- conv1: inputs straight from global (3 float2 pairs per lane) ----
  {
    const int p = (lane < 50) ? lane : 0;
    const long xb = m*100 + 2*p;
    const float2 x0v = *(const float2*)(x + xb);
    const float2 t0v = *(const float2*)(tm + xb);
    float2 xmv = {0.f, 0.f}, tmv = {0.f, 0.f};
    float2 xpv = {0.f, 0.f}, tpv = {0.f, 0.f};
    if (p > 0)  { xmv = *(const float2*)(x + xb - 2); tmv = *(const float2*)(tm + xb - 2); }
    if (p < 49) { xpv = *(const float2*)(x + xb + 2); tpv = *(const float2*)(tm + xb + 2); }
    const float a0 = xmv.x*tmv.x, c0 = xmv.y*tmv.y;
    const float a1 = x0v.x*t0v.x, c1 = x0v.y*t0v.y;
    const float a2 = xpv.x*tpv.x, c2 = xpv.y*tpv.y;
    const int row = lane + 1;                    // H row = pos+1
    const int sw  = ((row & 7) << 4) | (((row >> 3) & 1) << 7);  // 16-slot swizzle
    char* rbase = (char*)(Hw + row*128);
    #pragma unroll
    for (int g = 0; g < 4; ++g) {
      unsigned hi8[8], lo8[8];
      #pragma unroll
      for (int pr = 0; pr < 8; ++pr) {
        const int o = g*16 + pr*2;
        const float* wA = w1 + (long)o*6;       // wave-uniform -> s_load
        const float* wB = wA + 6;
        float sA = 0.f, sB = 0.f;
        sA = fmaf(wA[0], a0, sA); sA = fmaf(wA[1], a1, sA); sA = fmaf(wA[2], a2, sA);
        sA = fmaf(wA[3], c0, sA); sA = fmaf(wA[4], c1, sA); sA = fmaf(wA[5], c2, sA);
        sB = fmaf(wB[0], a0, sB); sB = fmaf(wB[1], a1, sB); sB = fmaf(wB[2], a2, sB);
        sB = fmaf(wB[3], c0, sB); sB = fmaf(wB[4], c1, sB); sB = fmaf(wB[5], c2, sB);
        const float hA = fmaxf(fmaf(imv, sA, b1[o]),     0.f);
        const float hB = fmaxf(fmaf(imv, sB, b1[o + 1]), 0.f);
        const unsigned h = pk2_bf16(hA, hB);
        const float ha = __uint_as_float(h << 16);
        const float hb = __uint_as_float(h & 0xffff0000u);
        lo8[pr] = pk2_bf16(hA - ha, hB - hb);
        hi8[pr] = h;
      }
      if (lane < 50) {
        *(short8*)(rbase + ((g*32)        ^ sw)) = *(short8*)&hi8[0];
        *(short8*)(rbase + ((g*32 + 16)   ^ sw)) = *(short8*)&hi8[4];
        *(short8*)(rbase + ((g*32 + 128)  ^ sw)) = *(short8*)&lo8[0];
        *(short8*)(rbase + ((g*32 + 144)  ^ sw)) = *(short8*)&lo8[4];
      }
    }
    if (lane == 50 || lane == 51) {          // zero halo rows 0 and 51 (swizzle-invariant)
      const int zr = (lane == 50) ? 0 : 51;
      short8 z8 = {};
      short8* d = (short8*)(Hw + zr*128);
      #pragma unroll
      for (int i = 0; i < 16; ++i) d[i] = z8;
    }
  }
  // intra-wave LDS write->read fence (wave-private slice; no barrier)
  asm volatile("s_waitcnt lgkmcnt(0)" ::: "memory");
  __builtin_amdgcn_sched_barrier(0);

  // ---- conv2 MFMA: all 4 (mt,nt) tiles of this wave's m ----
  f32x16 acc00, acc01, acc10, acc11;
  #pragma unroll
  for (int q = 0; q < 16; ++q) { acc00[q] = 0.f; acc01[q] = 0.f; acc10[q] = 0.f; acc11[q] = 0.f; }
  {
    const short8* bh8 = (const short8*)ebhi;
    const short8* bl8 = (const short8*)eblo;
    for (int t = 0; t < 3; ++t) {
      const int r0 = ln31 + t;                // 0..33, valid
      int r1 = 32 + ln31 + t;                 // 32..65 -> clamp to zero halo 51
      if (r1 > 51) r1 = 51;
      const int sw0 = ((r0 & 7) << 4) | (((r0 >> 3) & 1) << 7);
      const int sw1 = ((r1 & 7) << 4) | (((r1 >> 3) & 1) << 7);
      const char* b0p = (const char*)(Hw + r0*128);
      const char* b1p = (const char*)(Hw + r1*128);
      #pragma unroll
      for (int kt = 0; kt < 4; ++kt) {
        const int f0 = (t*2 + 0)*4 + kt;
        const int f1 = (t*2 + 1)*4 + kt;
        const int offh = kt*32 + half*16;
        const short8 Bh0 = bh8[f0*64 + lane], Bl0 = bl8[f0*64 + lane];
        const short8 Bh1 = bh8[f1*64 + lane], Bl1 = bl8[f1*64 + lane];
        const short8 ah0 = *(const short8*)(b0p + (offh ^ sw0));
        const short8 al0 = *(const short8*)(b0p + ((offh + 128) ^ sw0));
        const short8 ah1 = *(const short8*)(b1p + (offh ^ sw1));
        const short8 al1 = *(const short8*)(b1p + ((offh + 128) ^ sw1));
        acc00 = MFMA_BF16(ah0, Bh0, acc00, 0, 0, 0);
        acc00 = MFMA_BF16(ah0, Bl0, acc00, 0, 0, 0);
        acc00 = MFMA_BF16(al0, Bh0, acc00, 0, 0, 0);
        acc01 = MFMA_BF16(ah0, Bh1, acc01, 0, 0, 0);
        acc01 = MFMA_BF16(ah0, Bl1, acc01, 0, 0, 0);
        acc01 = MFMA_BF16(al0, Bh1, acc01, 0, 0, 0);
        acc10 = MFMA_BF16(ah1, Bh0, acc10, 0, 0, 0);
        acc10 = MFMA_BF16(ah1, Bl0, acc10, 0, 0, 0);
        acc10 = MFMA_BF16(al1, Bh0, acc10, 0, 0, 0);
        acc11 = MFMA_BF16(ah1, Bh1, acc11, 0, 0, 0);
        acc11 = MFMA_BF16(ah1, Bl1, acc11, 0, 0, 0);
        acc11 = MFMA_BF16(al1, Bh1, acc11, 0, 0, 0);
      }
    }
  }

  // ---- relu + bias + masked position-sum -> red[m][64] (f32, global) ----
  {
    const float bv0 = b2[ln31];
    const float bv1 = b2[32 + ln31];
    float s0 = 0.f, s1 = 0.f;
    #pragma unroll
    for (int r = 0; r < 16; ++r) {
      s0 += fmaxf(acc00[r] + bv0, 0.f);              // mt=0: pos 0..31 all valid
      s1 += fmaxf(acc01[r] + bv1, 0.f);
      const int mpos = 32 + rowfn(r, half);          // mt=1: keep pos<50
      const float v10 = fmaxf(acc10[r] + bv0, 0.f);
      const float v11 = fmaxf(acc11[r] + bv1, 0.f);
      if (mpos < 50) { s0 += v10; s1 += v11; }
    }
    s0 += __shfl_xor(s0, 32);
    s1 += __shfl_xor(s1, 32);
    if (half == 0) {
      red[m*64 + ln31]      = s0;
      red[m*64 + 32 + ln31] = s1;
    }
  }
}

// ---------------- latent: z = (latb + 0.02 * red @ latw^T) * im, f32 VALU ----------------
__global__ __launch_bounds__(256, 4) void latent_kernel(
    const float* __restrict__ red, const float* __restrict__ imask,
    const float* __restrict__ latw, const float* __restrict__ latb,
    ushort_t* __restrict__ zhi, ushort_t* __restrict__ zlo,
    float* __restrict__ rnp0, float* __restrict__ rnp1)
{
  __shared__ float s_r[64*64];
  __shared__ float s_im[64];
  const int tid = threadIdx.x;
  const long m0 = (long)blockIdx.x * 64;
  {
    const int r = tid >> 2, seg = tid & 3;
    const float4* src = (const float4*)(red + (m0 + r)*64 + seg*16);
    float4* dst = (float4*)(s_r + r*64 + seg*16);
    dst[0] = src[0]; dst[1] = src[1]; dst[2] = src[2]; dst[3] = src[3];
  }
  if (tid < 64) s_im[tid] = imask[m0 + tid];
  __syncthreads();

  const int e = tid & 127, mh = tid >> 7;
  const int lane = tid & 63;
  float4 W[16];
  const float4* wp = (const float4*)(latw + (long)e*64);
  #pragma unroll
  for (int q = 0; q < 16; ++q) W[q] = wp[q];
  const float lb = latb[e];

  for (int i = 0; i < 32; ++i) {
    const int ml = mh*32 + i;                         // wave-uniform
    const float4* rp = (const float4*)(s_r + ml*64);  // LDS broadcast
    float a = 0.f;
    #pragma unroll
    for (int q = 0; q < 16; ++q) {
      const float4 r4 = rp[q];
      a = fmaf(W[q].x, r4.x, a); a = fmaf(W[q].y, r4.y, a);
      a = fmaf(W[q].z, r4.z, a); a = fmaf(W[q].w, r4.w, a);
    }
    const float z = fmaf(0.02f, a, lb) * s_im[ml];
    h2u zh, zl; zh.h = (_Float16)z; zl.h = (_Float16)(z - (float)zh.h);
    const long mg = m0 + ml;
    zhi[mg*128 + e] = zh.u;
    zlo[mg*128 + e] = zl.u;
    float v = z*z;
    #pragma unroll
    for (int off = 32; off > 0; off >>= 1) v += __shfl_down(v, off);
    if (lane == 0) { if (e < 64) rnp0[mg] = v; else rnp1[mg] = v; }
  }
}

// ---------------- VQ: f16 3-pass MFMA, 32 rows x all 512 codes per block ----------------
__global__ __launch_bounds__(256) void vq_kernel(
    const ushort_t* __restrict__ zhi, const ushort_t* __restrict__ zlo,
    const ushort_t* __restrict__ cbhi, const ushort_t* __restrict__ cblo,
    const float* __restrict__ rnp0, const float* __restrict__ rnp1,
    const float* __restrict__ cbnorm, u64* __restrict__ gbest)
{
  __shared__ ushort_t s_ah[32*136];
  __shared__ ushort_t s_al[32*136];
  __shared__ float s_rn[32];
  __shared__ u64 s_best[32];
  const int tid = threadIdx.x;
  const int m0 = blockIdx.x * 32;
  {
    const short8* gh = (const short8*)(zhi + (long)m0*128);
    const short8* gl = (const short8*)(zlo + (long)m0*128);
    const int row = tid >> 3, c8 = (tid & 7)*2;
    ((short8*)s_ah)[row*17 + c8]     = gh[tid*2];
    ((short8*)s_ah)[row*17 + c8 + 1] = gh[tid*2 + 1];
    ((short8*)s_al)[row*17 + c8]     = gl[tid*2];
    ((short8*)s_al)[row*17 + c8 + 1] = gl[tid*2 + 1];
  }
  if (tid < 32) { s_rn[tid] = rnp0[m0 + tid] + rnp1[m0 + tid]; s_best[tid] = ~0ULL; }
  __syncthreads();

  const int wv = tid >> 6, lane = tid & 63;
  const int ln31 = lane & 31, half = lane >> 5;
  float rnv[16];
  #pragma unroll
  for (int r = 0; r < 16; ++r) rnv[r] = s_rn[rowfn(r, half)];

  u64 best[16];
  #pragma unroll
  for (int r = 0; r < 16; ++r) best[r] = ~0ULL;

  const short8* ch8 = (const short8*)cbhi;
  const short8* cl8 = (const short8*)cblo;
  for (int ct = 0; ct < 4; ++ct) {
    const int ntg = wv*4 + ct;
    half8 Bh[8], Bl[8];
    #pragma unroll
    for (int kt = 0; kt < 8; ++kt) {
      s2h a, b;
      a.s = ch8[(ntg*8 + kt)*64 + lane];
      b.s = cl8[(ntg*8 + kt)*64 + lane];
      Bh[kt] = a.h; Bl[kt] = b.h;
    }
    f32x16 acc;
    #pragma unroll
    for (int q = 0; q < 16; ++q) acc[q] = 0.f;
    const int base8 = ln31*17 + half;
    #pragma unroll
    for (int kt = 0; kt < 8; ++kt) {
      s2h ah, al;
      ah.s = ((const short8*)s_ah)[base8 + kt*2];
      al.s = ((const short8*)s_al)[base8 + kt*2];
      acc = __builtin_amdgcn_mfma_f32_32x32x16_f16(ah.h, Bh[kt], acc, 0, 0, 0);
      acc = __builtin_amdgcn_mfma_f32_32x32x16_f16(ah.h, Bl[kt], acc, 0, 0, 0);
      acc = __builtin_amdgcn_mfma_f32_32x32x16_f16(al.h, Bh[kt], acc, 0, 0, 0);
    }
    const int code = ntg*32 + ln31;
    const float nrm = cbnorm[code];
    #pragma unroll
    for (int r = 0; r < 16; ++r) {
      const float t = fmaf(-0.00390625f, acc[r], rnv[r]);  // A - p/256 (cb scaled x512)
      const float d = t + nrm;
      const u64 pk = ((u64)__float_as_uint(d) << 32) | (u64)(unsigned)code;
      if (pk < best[r]) best[r] = pk;
    }
  }
  #pragma unroll
  for (int r = 0; r < 16; ++r) atomicMin(&s_best[rowfn(r, half)], best[r]);
  __syncthreads();
  if (tid < 32) gbest[m0 + tid] = s_best[tid];
}

// ---------------- fused decoder: gather -> GEMM1 -> GEMM2 -> GEMM3 (h1/h2 in LDS) ----------------
// s_u: phases 0-1 = A1 gather (stride 136); phases 2-3 = h2 (stride 264).
// s_h1: GEMM1 output / GEMM2 input (stride 264). 68.2KB LDS -> 2 blocks/CU.
__global__ __launch_bounds__(256, 2) void decoder_kernel(
    const float* __restrict__ cb, const u64* __restrict__ gbest,
    const float* __restrict__ imask,
    const ushort_t* __restrict__ d1frag, const float* __restrict__ d1b,
    const ushort_t* __restrict__ d2frag, const float* __restrict__ d2b,
    const ushort_t* __restrict__ d3frag, const float* __restrict__ d3b,
    const float* __restrict__ x, const float* __restrict__ tm,
    float* __restrict__ xhat, float* __restrict__ out_idx,
    float* __restrict__ accums)
{
  __shared__ ushort_t s_u[64*264];
  __shared__ ushort_t s_h1[64*264];
  __shared__ int s_idx[64];
  __shared__ float s_act[64];
  __shared__ float s_p[4], s_w[4];
  const int tid = threadIdx.x;
  const long m0 = (long)blockIdx.x * 64;

  // ---- P0: indices, vq-loss, S_im; gather zq*im -> s_u (stride 136) ----
  if (tid < 64) {
    const u64 pk = gbest[m0 + tid];
    const int ii = (int)(unsigned)(pk & 0xffffffffULL);
    const float dd = __uint_as_float((unsigned)(pk >> 32));
    const float imv = imask[m0 + tid];
    s_idx[tid] = ii; s_act[tid] = imv;
    out_idx[m0 + tid] = (imv > 0.f) ? (float)ii : -1.0f;
    float vqp = 1.25f * dd * (1.0f/128.0f) * imv;
    float sim = imv;
    #pragma unroll
    for (int off = 32; off > 0; off >>= 1) {
      vqp += __shfl_down(vqp, off); sim += __shfl_down(sim, off);
    }
    if (tid == 0) { atomicAdd(&accums[1], vqp); atomicAdd(&accums[3], sim); }
  }
  __syncthreads();
  {
    const int row = tid >> 2, seg = tid & 3;
    const float4* src = (const float4*)(cb + (long)s_idx[row]*128 + seg*32);
    const float im = s_act[row];
    ushort_t tmp[32];
    #pragma unroll
    for (int q = 0; q < 8; ++q) {
      const float4 v = src[q];
      tmp[q*4+0] = bf16_rn(v.x*im); tmp[q*4+1] = bf16_rn(v.y*im);
      tmp[q*4+2] = bf16_rn(v.z*im); tmp[q*4+3] = bf16_rn(v.w*im);
    }
    short8* dst = (short8*)(s_u + row*136 + seg*32);
    #pragma unroll
    for (int q = 0; q < 4; ++q) dst[q] = *(short8*)&tmp[q*8];
  }
  __syncthreads();

  const int wv = tid >> 6, lane = tid & 63;
  const int ln31 = lane & 31, half = lane >> 5;

  // ---- P1: GEMM1 (K=128): h1 = relu(zq @ d1^T + b) -> s_h1 (stride 264) ----
  {
    const short8* bf = (const short8*)d1frag;
    #pragma unroll
    for (int nti = 0; nti < 2; ++nti) {
      const int ntg = wv + nti*4;
      short8 B[8];
      #pragma unroll
      for (int kt = 0; kt < 8; ++kt) B[kt] = bf[(ntg*8 + kt)*64 + lane];
      const float bv = d1b[ntg*32 + ln31];
      #pragma unroll
      for (int mtl = 0; mtl < 2; ++mtl) {
        f32x16 acc;
        #pragma unroll
        for (int q = 0; q < 16; ++q) acc[q] = 0.f;
        const int base8 = (mtl*32 + ln31)*17 + half;
        #pragma unroll
        for (int kt = 0; kt < 8; ++kt) {
          const short8 a = ((const short8*)s_u)[base8 + kt*2];
          acc = MFMA_BF16(a, B[kt], acc, 0, 0, 0);
        }
        const int col = ntg*32 + ln31;
        #pragma unroll
        for (int r = 0; r < 16; ++r) {
          const int row = mtl*32 + rowfn(r, half);
          s_h1[row*264 + col] = bf16_rn(fmaxf(acc[r] + bv, 0.f));
        }
      }
    }
  }
  __syncthreads();

  // ---- P2: GEMM2 (K=256): h2 = relu(h1 @ d2^T + b) -> s_u (stride 264) ----
  {
    const short8* bf = (const short8*)d2frag;
    #pragma unroll
    for (int nti = 0; nti < 2; ++nti) {
      const int ntg = wv + nti*4;
      short8 B[16];
      #pragma unroll
      for (int kt = 0; kt < 16; ++kt) B[kt] = bf[(ntg*16 + kt)*64 + lane];
      const float bv = d2b[ntg*32 + ln31];
      #pragma unroll
      for (int mtl = 0; mtl < 2; ++mtl) {
        f32x16 acc;
        #pragma unroll
        for (int q = 0; q < 16; ++q) acc[q] = 0.f;
        const int base8 = (mtl*32 + ln31)*33 + half;
        #pragma unroll
        for (int kt = 0; kt < 16; ++kt) {
          const short8 a = ((const short8*)s_h1)[base8 + kt*2];
          acc = MFMA_BF16(a, B[kt], acc, 0, 0, 0);
        }
        const int col = ntg*32 + ln31;
        #pragma unroll
        for (int r = 0; r < 16; ++r) {
          const int row = mtl*32 + rowfn(r, half);
          s_u[row*264 + col] = bf16_rn(fmaxf(acc[r] + bv, 0.f));
        }
      }
    }
  }
  __syncthreads();

  // ---- P3: GEMM3 (K=256, N=100): x_hat + recon loss + S_rw ----
  {
    const short8* bf = (const short8*)d3frag;
    const int ntg = wv;
    short8 B[16];
    #pragma unroll
    for (int kt = 0; kt < 16; ++kt) B[kt] = bf[(ntg*16 + kt)*64 + lane];
    const int col = ntg*32 + ln31;
    const float bv = (col < 100) ? d3b[col] : 0.f;
    float part = 0.f, wsum = 0.f;
    #pragma unroll
    for (int mtl = 0; mtl < 2; ++mtl) {
      f32x16 acc;
      #pragma unroll
      for (int q = 0; q < 16; ++q) acc[q] = 0.f;
      const int base8 = (mtl*32 + ln31)*33 + half;
      #pragma unroll
      for (int kt = 0; kt < 16; ++kt) {
        const short8 a = ((const short8*)s_u)[base8 + kt*2];
        acc = MFMA_BF16(a, B[kt], acc, 0, 0, 0);
      }
      if (col < 100) {
        #pragma unroll
        for (int r = 0; r < 16; ++r) {
          const long row = m0 + mtl*32 + rowfn(r, half);
          const float xh = acc[r] + bv;
          xhat[row*100 + col] = xh;
          const float wgt = imask[row] * tm[row*100 + col];
          const float df = xh - x[row*100 + col];
          part = fmaf(df*df, wgt, part);
          wsum += wgt;
        }
      }
    }
    #pragma unroll
    for (int off = 32; off > 0; off >>= 1) {
      part += __shfl_down(part, off); wsum += __shfl_down(wsum, off);
    }
    if (lane == 0) { s_p[wv] = part; s_w[wv] = wsum; }
    __syncthreads();
    if (tid == 0) {
      atomicAdd(&accums[0], s_p[0]+s_p[1]+s_p[2]+s_p[3]);
      atomicAdd(&accums[2], s_w[0]+s_w[1]+s_w[2]+s_w[3]);
    }
  }
}

// ---------------- finalize scalars ----------------
__global__ void finalize_kernel(const float* __restrict__ accums, float* __restrict__ out) {
  if (threadIdx.x == 0 && blockIdx.x == 0) {
    out[5120000] = accums[0] / fmaxf(accums[2], 1.0f);
    out[5120001] = accums[1] / fmaxf(accums[3], 1.0f);
  }
}

extern "C" void kernel_launch(void* const* d_in, const int* in_sizes, int n_in,
                              void* d_out, int out_size, void* d_ws, size_t ws_size,
                              hipStream_t stream)
{
  (void)in_sizes; (void)n_in; (void)out_size; (void)ws_size;
  const float* x     = (const float*)d_in[0];
  const float* tmsk  = (const float*)d_in[1];
  const float* imask = (const float*)d_in[2];
  const float* w1    = (const float*)d_in[3];
  const float* b1    = (const float*)d_in[4];
  const float* w2    = (const float*)d_in[5];
  const float* b2    = (const float*)d_in[6];
  const float* latw  = (const float*)d_in[7];
  const float* latb  = (const float*)d_in[8];
  const float* cb    = (const float*)d_in[9];
  const float* d1w   = (const float*)d_in[10];
  const float* d1b   = (const float*)d_in[11];
  const float* d2w   = (const float*)d_in[12];
  const float* d2b   = (const float*)d_in[13];
  const float* d3w   = (const float*)d_in[14];
  const float* d3b   = (const float*)d_in[15];
  float* out = (float*)d_out;
  float* ws  = (float*)d_ws;

  float*    rnp0   = ws + WS_RNP0;
  float*    rnp1   = ws + WS_RNP1;
  ushort_t* zhi    = (ushort_t*)(ws + WS_ZHI);
  ushort_t* zlo    = (ushort_t*)(ws + WS_ZLO);
  ushort_t* ebhi   = (ushort_t*)(ws + WS_ENCBHI);
  ushort_t* eblo   = (ushort_t*)(ws + WS_ENCBLO);
  ushort_t* cbhi   = (ushort_t*)(ws + WS_CBHI);
  ushort_t* cblo   = (ushort_t*)(ws + WS_CBLO);
  float*    cbnorm = ws + WS_CBNORM;
  ushort_t* d1f    = (ushort_t*)(ws + WS_D1F);
  ushort_t* d2f    = (ushort_t*)(ws + WS_D2F);
  ushort_t* d3f    = (ushort_t*)(ws + WS_D3F);
  float*    accums = ws + WS_ACCUMS;
  u64*      gbest  = (u64*)(ws + WS_GBEST);
  float*    red    = ws + WS_RED;
  float* xhat    = out;
  float* out_idx = out + 5120002;

  hipMemsetAsync(accums, 0, 8*sizeof(float), stream);

  prep_kernel<<<512, 256, 0, stream>>>(w2, cb, d1w, d2w, d3w,
                                       ebhi, eblo, cbhi, cblo, d1f, d2f, d3f, cbnorm);
  encoder_kernel<<<12800, 256, 0, stream>>>(x, tmsk, imask, w1, b1, ebhi, eblo, b2, red);
  latent_kernel<<<800, 256, 0, stream>>>(red, imask, latw, latb, zhi, zlo, rnp0, rnp1);
  vq_kernel<<<1600, 256, 0, stream>>>(zhi, zlo, cbhi, cblo, rnp0, rnp1, cbnorm, gbest);
  decoder_kernel<<<800, 256, 0, stream>>>(cb, gbest, imask, d1f, d1b, d2f, d2b,
                                          d3f, d3b, x, tmsk, xhat, out_idx, accums);
  finalize_kernel<<<1, 64, 0, stream>>>(accums, out);
}

// Round 9
// 428.559 us; speedup vs baseline: 1.4720x; 1.0197x over previous
//
#include <hip/hip_runtime.h>
#include <stdint.h>

typedef unsigned long long u64;
typedef unsigned short ushort_t;
typedef __attribute__((ext_vector_type(8))) short short8;
typedef __attribute__((ext_vector_type(8))) _Float16 half8;
typedef __attribute__((ext_vector_type(16))) float f32x16;

// Dims: B=512,N=100 -> M=51200; T=100, L=50 conv pos, HE=64, E=128, NE=512, HD=256.

// ---------------- workspace layout (float offsets) ----------------
#define WS_ENCBHI   6656000ll    // 12288 ushort = 6144 f              -> end 6,662,144
#define WS_ENCBLO   6662144ll    // 6144 f                             -> end 6,668,288
#define WS_CBHI     6668288ll    // 65536 ushort = 32768 f             -> end 6,701,056
#define WS_CBLO     6701056ll    // 32768 f                            -> end 6,733,824
#define WS_CBNORM   6733824ll    // 512 f                              -> end 6,734,336
#define WS_D1F      6734336ll    // 32768 ushort = 16384 f             -> end 6,750,720
#define WS_D2F      6750720ll    // 65536 ushort = 32768 f             -> end 6,783,488
#define WS_D3F      6783488ll    // 32768 ushort = 16384 f             -> end 6,799,872
#define WS_ACCUMS   6799872ll    // 8 f32                              -> end 6,799,880
#define WS_RED      6902280ll    // red[51200*64] f32 = 3,276,800 f    -> end 10,179,080

__device__ __host__ inline ushort_t bf16_rn(float v) {
  unsigned u = __float_as_uint(v);
  unsigned r = (u + 0x7fffu + ((u >> 16) & 1u)) >> 16;
  return (ushort_t)r;
}
union h2u { _Float16 h; unsigned short u; };
union s2h { short8 s; half8 h; };

// packed RNE f32x2 -> bf16x2 (v_cvt_pk_bf16_f32); low 16 bits = a, high = b.
__device__ inline unsigned pk2_bf16(float a, float b) {
  unsigned r;
  asm("v_cvt_pk_bf16_f32 %0, %1, %2" : "=v"(r) : "v"(a), "v"(b));
  return r;
}

__device__ inline int rowfn(int r, int half) { return (r & 3) + 8*(r >> 2) + 4*half; }

#define MFMA_BF16 __builtin_amdgcn_mfma_f32_32x32x16_bf16
#define MFMA_F16  __builtin_amdgcn_mfma_f32_32x32x16_f16

// ---------------- prep: frag-pack all weights + codebook norms ----------------
__global__ __launch_bounds__(256) void prep_kernel(
    const float* __restrict__ w2, const float* __restrict__ cb,
    const float* __restrict__ d1w, const float* __restrict__ d2w,
    const float* __restrict__ d3w,
    ushort_t* __restrict__ ebhi, ushort_t* __restrict__ eblo,
    ushort_t* __restrict__ cbhi, ushort_t* __restrict__ cblo,
    ushort_t* __restrict__ d1f, ushort_t* __restrict__ d2f,
    ushort_t* __restrict__ d3f, float* __restrict__ cbnorm)
{
  const int total = 12288 + 65536 + 32768 + 65536 + 32768 + 512;
  for (int i = blockIdx.x*256 + threadIdx.x; i < total; i += gridDim.x*256) {
    int idx = i;
    if (idx < 12288) {
      // encoder conv2 B-frags (bf16 hi/lo), 32x32x16: f=((t*2+nt)*4+kt)
      int j = idx & 7, l6 = (idx >> 3) & 63, f = idx >> 9;
      int kt = f & 3, ntt = (f >> 2) & 1, t = f >> 3;
      int oc = ntt*32 + (l6 & 31);
      int ic = kt*16 + (l6 >> 5)*8 + j;
      float v = w2[(oc*64 + ic)*3 + t];
      ushort_t hi = bf16_rn(v);
      float hf = __uint_as_float(((unsigned)hi) << 16);
      ebhi[idx] = hi; eblo[idx] = bf16_rn(v - hf); continue;
    }
    idx -= 12288;
    if (idx < 65536) {
      // codebook f16 hi/lo frags, scaled x512: ntg16 x kt8
      int j = idx & 7, l6 = (idx >> 3) & 63, f = idx >> 9;
      int kt = f & 7, ntg = f >> 3;
      int k = kt*16 + (l6 >> 5)*8 + j;
      int n = ntg*32 + (l6 & 31);
      float v = cb[n*128 + k] * 512.0f;
      h2u a, b; a.h = (_Float16)v;
      b.h = (_Float16)(v - (float)a.h);
      cbhi[idx] = a.u; cblo[idx] = b.u; continue;
    }
    idx -= 65536;
    if (idx < 32768) {
      int j = idx & 7, l6 = (idx >> 3) & 63, f = idx >> 9;
      int kt = f & 7, ntg = f >> 3;
      int k = kt*16 + (l6 >> 5)*8 + j;
      int n = ntg*32 + (l6 & 31);
      d1f[idx] = bf16_rn(d1w[n*128 + k]); continue;
    }
    idx -= 32768;
    if (idx < 65536) {
      int j = idx & 7, l6 = (idx >> 3) & 63, f = idx >> 9;
      int kt = f & 15, ntg = f >> 4;
      int k = kt*16 + (l6 >> 5)*8 + j;
      int n = ntg*32 + (l6 & 31);
      d2f[idx] = bf16_rn(d2w[n*256 + k]); continue;
    }
    idx -= 65536;
    if (idx < 32768) {
      int j = idx & 7, l6 = (idx >> 3) & 63, f = idx >> 9;
      int kt = f & 15, ntg = f >> 4;
      int k = kt*16 + (l6 >> 5)*8 + j;
      int n = ntg*32 + (l6 & 31);
      d3f[idx] = (n < 100) ? bf16_rn(d3w[n*256 + k]) : (ushort_t)0; continue;
    }
    idx -= 32768;
    { double s = 0.0; const float* c = cb + idx*128;
      for (int e = 0; e < 128; ++e) { double v = (double)c[e]; s += v*v; }
      cbnorm[idx] = (float)s; }
  }
}

// ---------------- encoder v6: one wave per m, zero barriers, 3 blocks/CU ----------------
// Per-wave H slice: 52 rows x 256B (hi | lo planes), 16-slot XOR swizzle
// sw = ((row&7)<<4) | (((row>>3)&1)<<7). Zero halo rows 0/51 swizzle-invariant.
// LDS 53,248 B -> exactly 3 blocks/CU. No __syncthreads; intra-wave fence only.
__global__ __launch_bounds__(256, 3) void encoder_kernel(
    const float* __restrict__ x, const float* __restrict__ tm,
    const float* __restrict__ imask,
    const float* w1, const float* b1,
    const ushort_t* __restrict__ ebhi, const ushort_t* __restrict__ eblo,
    const float* b2, float* __restrict__ red)
{
  __shared__ ushort_t s_H[4][52*128];   // 53,248 B total
  const int tid  = threadIdx.x;
  const int wv   = __builtin_amdgcn_readfirstlane((int)(tid >> 6));
  const int lane = tid & 63;
  const int ln31 = lane & 31, half = lane >> 5;
  const long m   = (long)blockIdx.x*4 + wv;     // wave-uniform
  const float imv = imask[m];                   // scalar load
  ushort_t* Hw  = s_H[wv];

  // ---- conv1: inputs straight from global (3 float2 pairs per lane) ----
  {
    const int p = (lane < 50) ? lane : 0;
    const long xb = m*100 + 2*p;
    const float2 x0v = *(const float2*)(x + xb);
    const float2 t0v = *(const float2*)(tm + xb);
    float2 xmv = {0.f, 0.f}, tmv = {0.f, 0.f};
    float2 xpv = {0.f, 0.f}, tpv = {0.f, 0.f};
    if (p > 0)  { xmv = *(const float2*)(x + xb - 2); tmv = *(const float2*)(tm + xb - 2); }
    if (p < 49) { xpv = *(const float2*)(x + xb + 2); tpv = *(const float2*)(tm + xb + 2); }
    const float a0 = xmv.x*tmv.x, c0 = xmv.y*tmv.y;
    const float a1 = x0v.x*t0v.x, c1 = x0v.y*t0v.y;
    const float a2 = xpv.x*tpv.x, c2 = xpv.y*tpv.y;
    const int row = lane + 1;                    // H row = pos+1
    const int sw  = ((row & 7) << 4) | (((row >> 3) & 1) << 7);  // 16-slot swizzle
    char* rbase = (char*)(Hw + row*128);
    #pragma unroll
    for (int g = 0; g < 4; ++g) {
      unsigned hi8[8], lo8[8];
      #pragma unroll
      for (int pr = 0; pr < 8; ++pr) {
        const int o = g*16 + pr*2;
        const float* wA = w1 + (long)o*6;       // wave-uniform -> s_load
        const float* wB = wA + 6;
        float sA = 0.f, sB = 0.f;
        sA = fmaf(wA[0], a0, sA); sA = fmaf(wA[1], a1, sA); sA = fmaf(wA[2], a2, sA);
        sA = fmaf(wA[3], c0, sA); sA = fmaf(wA[4], c1, sA); sA = fmaf(wA[5], c2, sA);
        sB = fmaf(wB[0], a0, sB); sB = fmaf(wB[1], a1, sB); sB = fmaf(wB[2], a2, sB);
        sB = fmaf(wB[3], c0, sB); sB = fmaf(wB[4], c1, sB); sB = fmaf(wB[5], c2, sB);
        const float hA = fmaxf(fmaf(imv, sA, b1[o]),     0.f);
        const float hB = fmaxf(fmaf(imv, sB, b1[o + 1]), 0.f);
        const unsigned h = pk2_bf16(hA, hB);
        const float ha = __uint_as_float(h << 16);
        const float hb = __uint_as_float(h & 0xffff0000u);
        lo8[pr] = pk2_bf16(hA - ha, hB - hb);
        hi8[pr] = h;
      }
      if (lane < 50) {
        *(short8*)(rbase + ((g*32)        ^ sw)) = *(short8*)&hi8[0];
        *(short8*)(rbase + ((g*32 + 16)   ^ sw)) = *(short8*)&hi8[4];
        *(short8*)(rbase + ((g*32 + 128)  ^ sw)) = *(short8*)&lo8[0];
        *(short8*)(rbase + ((g*32 + 144)  ^ sw)) = *(short8*)&lo8[4];
      }
    }
    if (lane == 50 || lane == 51) {          // zero halo rows 0 and 51 (swizzle-invariant)
      const int zr = (lane == 50) ? 0 : 51;
      short8 z8 = {};
      short8* d = (short8*)(Hw + zr*128);
      #pragma unroll
      for (int i = 0; i < 16; ++i) d[i] = z8;
    }
  }
  // intra-wave LDS write->read fence (wave-private slice; no barrier)
  asm volatile("s_waitcnt lgkmcnt(0)" ::: "memory");
  __builtin_amdgcn_sched_barrier(0);

  // ---- conv2 MFMA: all 4 (mt,nt) tiles of this wave's m ----
  f32x16 acc00, acc01, acc10, acc11;
  #pragma unroll
  for (int q = 0; q < 16; ++q) { acc00[q] = 0.f; acc01[q] = 0.f; acc10[q] = 0.f; acc11[q] = 0.f; }
  {
    const short8* bh8 = (const short8*)ebhi;
    const short8* bl8 = (const short8*)eblo;
    for (int t = 0; t < 3; ++t) {
      const int r0 = ln31 + t;                // 0..33, valid
      int r1 = 32 + ln31 + t;                 // 32..65 -> clamp to zero halo 51
      if (r1 > 51) r1 = 51;
      const int sw0 = ((r0 & 7) << 4) | (((r0 >> 3) & 1) << 7);
      const int sw1 = ((r1 & 7) << 4) | (((r1 >> 3) & 1) << 7);
      const char* b0p = (const char*)(Hw + r0*128);
      const char* b1p = (const char*)(Hw + r1*128);
      #pragma unroll
      for (int kt = 0; kt < 4; ++kt) {
        const int f0 = (t*2 + 0)*4 + kt;
        const int f1 = (t*2 + 1)*4 + kt;
        const int offh = kt*32 + half*16;
        const short8 Bh0 = bh8[f0*64 + lane], Bl0 = bl8[f0*64 + lane];
        const short8 Bh1 = bh8[f1*64 + lane], Bl1 = bl8[f1*64 + lane];
        const short8 ah0 = *(const short8*)(b0p + (offh ^ sw0));
        const short8 al0 = *(const short8*)(b0p + ((offh + 128) ^ sw0));
        const short8 ah1 = *(const short8*)(b1p + (offh ^ sw1));
        const short8 al1 = *(const short8*)(b1p + ((offh + 128) ^ sw1));
        acc00 = MFMA_BF16(ah0, Bh0, acc00, 0, 0, 0);
        acc00 = MFMA_BF16(ah0, Bl0, acc00, 0, 0, 0);
        acc00 = MFMA_BF16(al0, Bh0, acc00, 0, 0, 0);
        acc01 = MFMA_BF16(ah0, Bh1, acc01, 0, 0, 0);
        acc01 = MFMA_BF16(ah0, Bl1, acc01, 0, 0, 0);
        acc01 = MFMA_BF16(al0, Bh1, acc01, 0, 0, 0);
        acc10 = MFMA_BF16(ah1, Bh0, acc10, 0, 0, 0);
        acc10 = MFMA_BF16(ah1, Bl0, acc10, 0, 0, 0);
        acc10 = MFMA_BF16(al1, Bh0, acc10, 0, 0, 0);
        acc11 = MFMA_BF16(ah1, Bh1, acc11, 0, 0, 0);
        acc11 = MFMA_BF16(ah1, Bl1, acc11, 0, 0, 0);
        acc11 = MFMA_BF16(al1, Bh1, acc11, 0, 0, 0);
      }
    }
  }

  // ---- relu + bias + masked position-sum -> red[m][64] (f32, global) ----
  {
    const float bv0 = b2[ln31];
    const float bv1 = b2[32 + ln31];
    float s0 = 0.f, s1 = 0.f;
    #pragma unroll
    for (int r = 0; r < 16; ++r) {
      s0 += fmaxf(acc00[r] + bv0, 0.f);              // mt=0: pos 0..31 all valid
      s1 += fmaxf(acc01[r] + bv1, 0.f);
      const int mpos = 32 + rowfn(r, half);          // mt=1: keep pos<50
      const float v10 = fmaxf(acc10[r] + bv0, 0.f);
      const float v11 = fmaxf(acc11[r] + bv1, 0.f);
      if (mpos < 50) { s0 += v10; s1 += v11; }
    }
    s0 += __shfl_xor(s0, 32);
    s1 += __shfl_xor(s1, 32);
    if (half == 0) {
      red[m*64 + ln31]      = s0;
      red[m*64 + 32 + ln31] = s1;
    }
  }
}

// ---------------- fused latent -> VQ -> decoder (64 m per block) ----------------
// LDS region aliasing by phase:
//   region1 (33792B): [s_r 16K | s_al 17.4K] (latent->vq)  ->  s_u (gather/GEMMs)
//   region2 (33792B): [s_ah 17.4K]           (latent->vq)  ->  s_h1 (GEMM1/2)
// All arithmetic copied verbatim from the R7-passing latent/vq/decoder kernels
// (bitwise-identical order; only data routing changed global->LDS).
__global__ __launch_bounds__(256, 2) void vqdec_kernel(
    const float* __restrict__ red, const float* __restrict__ imask,
    const float* __restrict__ latw, const float* __restrict__ latb,
    const ushort_t* __restrict__ cbhi, const ushort_t* __restrict__ cblo,
    const float* __restrict__ cbnorm, const float* __restrict__ cb,
    const ushort_t* __restrict__ d1frag, const float* __restrict__ d1b,
    const ushort_t* __restrict__ d2frag, const float* __restrict__ d2b,
    const ushort_t* __restrict__ d3frag, const float* __restrict__ d3b,
    const float* __restrict__ x, const float* __restrict__ tm,
    float* __restrict__ xhat, float* __restrict__ out_idx,
    float* __restrict__ accums)
{
  __shared__ __attribute__((aligned(16))) ushort_t s_reg1[64*264];
  __shared__ __attribute__((aligned(16))) ushort_t s_reg2[64*264];
  __shared__ int s_idx[64];
  __shared__ float s_act[64];
  __shared__ float s_rn0[64], s_rn1[64];
  __shared__ u64 s_best[64];
  __shared__ float s_im[64];
  __shared__ float s_p[4], s_w[4];

  float*    s_r  = (float*)s_reg1;        // 4096 f32 (latent input)
  ushort_t* s_al = s_reg1 + 8192;         // 8704 ush (z lo frags), ends at 16896
  ushort_t* s_ah = s_reg2;                // 8704 ush (z hi frags)
  ushort_t* s_u  = s_reg1;                // gather A1 (stride 136) / h2 (stride 264)
  ushort_t* s_h1 = s_reg2;                // h1 (stride 264)

  const int tid = threadIdx.x;
  const long m0 = (long)blockIdx.x * 64;
  const int wv = tid >> 6, lane = tid & 63;
  const int ln31 = lane & 31, half = lane >> 5;

  // ---- stage: red -> s_r, imask -> s_im, init s_best ----
  {
    const int r = tid >> 2, seg = tid & 3;
    const float4* src = (const float4*)(red + (m0 + r)*64 + seg*16);
    float4* dst = (float4*)(s_r + r*64 + seg*16);
    dst[0] = src[0]; dst[1] = src[1]; dst[2] = src[2]; dst[3] = src[3];
  }
  if (tid < 64) { s_im[tid] = imask[m0 + tid]; s_best[tid] = ~0ULL; }
  __syncthreads();

  // ---- latent: z -> f16 hi/lo frags in LDS + rownorm partials ----
  {
    const int e = tid & 127, mh = tid >> 7;
    float4 W[16];
    const float4* wp = (const float4*)(latw + (long)e*64);
    #pragma unroll
    for (int q = 0; q < 16; ++q) W[q] = wp[q];
    const float lb = latb[e];
    for (int i = 0; i < 32; ++i) {
      const int ml = mh*32 + i;                        // wave-uniform
      const float4* rp = (const float4*)(s_r + ml*64); // LDS broadcast
      float a = 0.f;
      #pragma unroll
      for (int q = 0; q < 16; ++q) {
        const float4 r4 = rp[q];
        a = fmaf(W[q].x, r4.x, a); a = fmaf(W[q].y, r4.y, a);
        a = fmaf(W[q].z, r4.z, a); a = fmaf(W[q].w, r4.w, a);
      }
      const float z = fmaf(0.02f, a, lb) * s_im[ml];
      h2u zh, zl; zh.h = (_Float16)z; zl.h = (_Float16)(z - (float)zh.h);
      s_ah[ml*136 + e] = zh.u;
      s_al[ml*136 + e] = zl.u;
      float v = z*z;
      #pragma unroll
      for (int off = 32; off > 0; off >>= 1) v += __shfl_down(v, off);
      if (lane == 0) { if (e < 64) s_rn0[ml] = v; else s_rn1[ml] = v; }
    }
  }
  __syncthreads();

  // ---- VQ: 2 row-tiles per wave x own 128 codes; argmin -> s_best ----
  {
    const short8* ch8 = (const short8*)cbhi;
    const short8* cl8 = (const short8*)cblo;
    #pragma unroll
    for (int mtl = 0; mtl < 2; ++mtl) {
      float rnv[16];
      #pragma unroll
      for (int r = 0; r < 16; ++r) {
        const int g = mtl*32 + rowfn(r, half);
        rnv[r] = s_rn0[g] + s_rn1[g];
      }
      u64 best[16];
      #pragma unroll
      for (int r = 0; r < 16; ++r) best[r] = ~0ULL;
      for (int ct = 0; ct < 4; ++ct) {
        const int ntg = wv*4 + ct;
        half8 Bh[8], Bl[8];
        #pragma unroll
        for (int kt = 0; kt < 8; ++kt) {
          s2h a, b;
          a.s = ch8[(ntg*8 + kt)*64 + lane];
          b.s = cl8[(ntg*8 + kt)*64 + lane];
          Bh[kt] = a.h; Bl[kt] = b.h;
        }
        f32x16 acc;
        #pragma unroll
        for (int q = 0; q < 16; ++q) acc[q] = 0.f;
        const int base8 = (mtl*32 + ln31)*17 + half;
        #pragma unroll
        for (int kt = 0; kt < 8; ++kt) {
          s2h ah, al;
          ah.s = ((const short8*)s_ah)[base8 + kt*2];
          al.s = ((const short8*)s_al)[base8 + kt*2];
          acc = MFMA_F16(ah.h, Bh[kt], acc, 0, 0, 0);
          acc = MFMA_F16(ah.h, Bl[kt], acc, 0, 0, 0);
          acc = MFMA_F16(al.h, Bh[kt], acc, 0, 0, 0);
        }
        const int code = ntg*32 + ln31;
        const float nrm = cbnorm[code];
        #pragma unroll
        for (int r = 0; r < 16; ++r) {
          const float t = fmaf(-0.00390625f, acc[r], rnv[r]);  // A - p/256 (cb x512)
          const float d = t + nrm;
          const u64 pk = ((u64)__float_as_uint(d) << 32) | (u64)(unsigned)code;
          if (pk < best[r]) best[r] = pk;
        }
      }
      #pragma unroll
      for (int r = 0; r < 16; ++r)
        atomicMin(&s_best[mtl*32 + rowfn(r, half)], best[r]);
    }
  }
  __syncthreads();

  // ---- P0: indices, vq-loss, S_im; gather zq*im -> s_u (stride 136) ----
  if (tid < 64) {
    const u64 pk = s_best[tid];
    const int ii = (int)(unsigned)(pk & 0xffffffffULL);
    const float dd = __uint_as_float((unsigned)(pk >> 32));
    const float imv = s_im[tid];
    s_idx[tid] = ii; s_act[tid] = imv;
    out_idx[m0 + tid] = (imv > 0.f) ? (float)ii : -1.0f;
    float vqp = 1.25f * dd * (1.0f/128.0f) * imv;
    float sim = imv;
    #pragma unroll
    for (int off = 32; off > 0; off >>= 1) {
      vqp += __shfl_down(vqp, off); sim += __shfl_down(sim, off);
    }
    if (tid == 0) { atomicAdd(&accums[1], vqp); atomicAdd(&accums[3], sim); }
  }
  __syncthreads();
  {
    const int row = tid >> 2, seg = tid & 3;
    const float4* src = (const float4*)(cb + (long)s_idx[row]*128 + seg*32);
    const float im = s_act[row];
    ushort_t tmp[32];
    #pragma unroll
    for (int q = 0; q < 8; ++q) {
      const float4 v = src[q];
      tmp[q*4+0] = bf16_rn(v.x*im); tmp[q*4+1] = bf16_rn(v.y*im);
      tmp[q*4+2] = bf16_rn(v.z*im); tmp[q*4+3] = bf16_rn(v.w*im);
    }
    short8* dst = (short8*)(s_u + row*136 + seg*32);
    #pragma unroll
    for (int q = 0; q < 4; ++q) dst[q] = *(short8*)&tmp[q*8];
  }
  __syncthreads();

  // ---- P1: GEMM1 (K=128): h1 = relu(zq @ d1^T + b) -> s_h1 (stride 264) ----
  {
    const short8* bf = (const short8*)d1frag;
    #pragma unroll
    for (int nti = 0; nti < 2; ++nti) {
      const int ntg = wv + nti*4;
      short8 B[8];
      #pragma unroll
      for (int kt = 0; kt < 8; ++kt) B[kt] = bf[(ntg*8 + kt)*64 + lane];
      const float bv = d1b[ntg*32 + ln31];
      #pragma unroll
      for (int mtl = 0; mtl < 2; ++mtl) {
        f32x16 acc;
        #pragma unroll
        for (int q = 0; q < 16; ++q) acc[q] = 0.f;
        const int base8 = (mtl*32 + ln31)*17 + half;
        #pragma unroll
        for (int kt = 0; kt < 8; ++kt) {
          const short8 a = ((const short8*)s_u)[base8 + kt*2];
          acc = MFMA_BF16(a, B[kt], acc, 0, 0, 0);
        }
        const int col = ntg*32 + ln31;
        #pragma unroll
        for (int r = 0; r < 16; ++r) {
          const int row = mtl*32 + rowfn(r, half);
          s_h1[row*264 + col] = bf16_rn(fmaxf(acc[r] + bv, 0.f));
        }
      }
    }
  }
  __syncthreads();

  // ---- P2: GEMM2 (K=256): h2 = relu(h1 @ d2^T + b) -> s_u (stride 264) ----
  {
    const short8* bf = (const short8*)d2frag;
    #pragma unroll
    for (int nti = 0; nti < 2; ++nti) {
      const int ntg = wv + nti*4;
      short8 B[16];
      #pragma unroll
      for (int kt = 0; kt < 16; ++kt) B[kt] = bf[(ntg*16 + kt)*64 + lane];
      const float bv = d2b[ntg*32 + ln31];
      #pragma unroll
      for (int mtl = 0; mtl < 2; ++mtl) {
        f32x16 acc;
        #pragma unroll
        for (int q = 0; q < 16; ++q) acc[q] = 0.f;
        const int base8 = (mtl*32 + ln31)*33 + half;
        #pragma unroll
        for (int kt = 0; kt < 16; ++kt) {
          const short8 a = ((const short8*)s_h1)[base8 + kt*2];
          acc = MFMA_BF16(a, B[kt], acc, 0, 0, 0);
        }
        const int col = ntg*32 + ln31;
        #pragma unroll
        for (int r = 0; r < 16; ++r) {
          const int row = mtl*32 + rowfn(r, half);
          s_u[row*264 + col] = bf16_rn(fmaxf(acc[r] + bv, 0.f));
        }
      }
    }
  }
  __syncthreads();

  // ---- P3: GEMM3 (K=256, N=100): x_hat + recon loss + S_rw ----
  {
    const short8* bf = (const short8*)d3frag;
    const int ntg = wv;
    short8 B[16];
    #pragma unroll
    for (int kt = 0; kt < 16; ++kt) B[kt] = bf[(ntg*16 + kt)*64 + lane];
    const int col = ntg*32 + ln31;
    const float bv = (col < 100) ? d3b[col] : 0.f;
    float part = 0.f, wsum = 0.f;
    #pragma unroll
    for (int mtl = 0; mtl < 2; ++mtl) {
      f32x16 acc;
      #pragma unroll
      for (int q = 0; q < 16; ++q) acc[q] = 0.f;
      const int base8 = (mtl*32 + ln31)*33 + half;
      #pragma unroll
      for (int kt = 0; kt < 16; ++kt) {
        const short8 a = ((const short8*)s_u)[base8 + kt*2];
        acc = MFMA_BF16(a, B[kt], acc, 0, 0, 0);
      }
      if (col < 100) {
        #pragma unroll
        for (int r = 0; r < 16; ++r) {
          const long row = m0 + mtl*32 + rowfn(r, half);
          const float xh = acc[r] + bv;
          xhat[row*100 + col] = xh;
          const float wgt = imask[row] * tm[row*100 + col];
          const float df = xh - x[row*100 + col];
          part = fmaf(df*df, wgt, part);
          wsum += wgt;
        }
      }
    }
    #pragma unroll
    for (int off = 32; off > 0; off >>= 1) {
      part += __shfl_down(part, off); wsum += __shfl_down(wsum, off);
    }
    if (lane == 0) { s_p[wv] = part; s_w[wv] = wsum; }
    __syncthreads();
    if (tid == 0) {
      atomicAdd(&accums[0], s_p[0]+s_p[1]+s_p[2]+s_p[3]);
      atomicAdd(&accums[2], s_w[0]+s_w[1]+s_w[2]+s_w[3]);
    }
  }
}

// ---------------- finalize scalars ----------------
__global__ void finalize_kernel(const float* __restrict__ accums, float* __restrict__ out) {
  if (threadIdx.x == 0 && blockIdx.x == 0) {
    out[5120000] = accums[0] / fmaxf(accums[2], 1.0f);
    out[5120001] = accums[1] / fmaxf(accums[3], 1.0f);
  }
}

extern "C" void kernel_launch(void* const* d_in, const int* in_sizes, int n_in,
                              void* d_out, int out_size, void* d_ws, size_t ws_size,
                              hipStream_t stream)
{
  (void)in_sizes; (void)n_in; (void)out_size; (void)ws_size;
  const float* x     = (const float*)d_in[0];
  const float* tmsk  = (const float*)d_in[1];
  const float* imask = (const float*)d_in[2];
  const float* w1    = (const float*)d_in[3];
  const float* b1    = (const float*)d_in[4];
  const float* w2    = (const float*)d_in[5];
  const float* b2    = (const float*)d_in[6];
  const float* latw  = (const float*)d_in[7];
  const float* latb  = (const float*)d_in[8];
  const float* cb    = (const float*)d_in[9];
  const float* d1w   = (const float*)d_in[10];
  const float* d1b   = (const float*)d_in[11];
  const float* d2w   = (const float*)d_in[12];
  const float* d2b   = (const float*)d_in[13];
  const float* d3w   = (const float*)d_in[14];
  const float* d3b   = (const float*)d_in[15];
  float* out = (float*)d_out;
  float* ws  = (float*)d_ws;

  ushort_t* ebhi   = (ushort_t*)(ws + WS_ENCBHI);
  ushort_t* eblo   = (ushort_t*)(ws + WS_ENCBLO);
  ushort_t* cbhi   = (ushort_t*)(ws + WS_CBHI);
  ushort_t* cblo   = (ushort_t*)(ws + WS_CBLO);
  float*    cbnorm = ws + WS_CBNORM;
  ushort_t* d1f    = (ushort_t*)(ws + WS_D1F);
  ushort_t* d2f    = (ushort_t*)(ws + WS_D2F);
  ushort_t* d3f    = (ushort_t*)(ws + WS_D3F);
  float*    accums = ws + WS_ACCUMS;
  float*    red    = ws + WS_RED;
  float* xhat    = out;
  float* out_idx = out + 5120002;

  hipMemsetAsync(accums, 0, 8*sizeof(float), stream);

  prep_kernel<<<512, 256, 0, stream>>>(w2, cb, d1w, d2w, d3w,
                                       ebhi, eblo, cbhi, cblo, d1f, d2f, d3f, cbnorm);
  encoder_kernel<<<12800, 256, 0, stream>>>(x, tmsk, imask, w1, b1, ebhi, eblo, b2, red);
  vqdec_kernel<<<800, 256, 0, stream>>>(red, imask, latw, latb, cbhi, cblo, cbnorm, cb,
                                        d1f, d1b, d2f, d2b, d3f, d3b, x, tmsk,
                                        xhat, out_idx, accums);
  finalize_kernel<<<1, 64, 0, stream>>>(accums, out);
}